// Round 1
// 173.393 us; speedup vs baseline: 1.0168x; 1.0168x over previous
//
#include <hip/hip_runtime.h>
#include <hip/hip_bf16.h>
#include <hip/hip_fp16.h>

// Problem constants (B=8, T=4096, Din=Dout=256, WINDOW=2)
#define BDIM 8
#define TDIM 4096
#define DDIM 256
#define MDIM (BDIM * TDIM)      // 32768
#define NCHUNK 256              // chunks along T for the parallel scan
#define LCHUNK (TDIM / NCHUNK)  // 16

typedef _Float16 f16x8 __attribute__((ext_vector_type(8)));
typedef _Float16 f16x4 __attribute__((ext_vector_type(4)));
typedef float f32x4 __attribute__((ext_vector_type(4)));

__device__ __forceinline__ float sigmoid_(float x) {
    return 1.0f / (1.0f + __expf(-x));
}
__device__ __forceinline__ float tanh_(float x) {
    return 2.0f / (1.0f + __expf(-2.0f * x)) - 1.0f;
}

#define GLOAD_LDS16(g, l)                                                    \
    __builtin_amdgcn_global_load_lds(                                        \
        (const __attribute__((address_space(1))) void*)(g),                  \
        (__attribute__((address_space(3))) void*)(l), 16, 0, 0)

// ---------------------------------------------------------------------------
// x [B,T,D] fp32 -> xpad [B,T+1,D] f16 with a zero row at t'=0.
// ---------------------------------------------------------------------------
__global__ __launch_bounds__(64) void convert_x(const float* __restrict__ x,
                                                _Float16* __restrict__ xpad) {
    const int tp = blockIdx.x;  // 0..4096
    const int b = blockIdx.y;
    const int q = threadIdx.x;  // 0..63 -> 4 floats each
    float4 v = make_float4(0.f, 0.f, 0.f, 0.f);
    if (tp > 0)
        v = *(const float4*)(x + ((size_t)b * TDIM + tp - 1) * DDIM + q * 4);
    f16x4 h;
    h[0] = (_Float16)v.x; h[1] = (_Float16)v.y;
    h[2] = (_Float16)v.z; h[3] = (_Float16)v.w;
    *(f16x4*)(xpad + ((size_t)b * (TDIM + 1) + tp) * DDIM + q * 4) = h;
}

// ---------------------------------------------------------------------------
// W[g][w][kin][n] fp32 -> Wt[g][n][w*256+kin] f16 (contiguous in k).
// ---------------------------------------------------------------------------
__global__ __launch_bounds__(256) void convert_w(
    const float* __restrict__ Wz, const float* __restrict__ Wf,
    const float* __restrict__ Wo, _Float16* __restrict__ Wt) {
    const int idx = blockIdx.x * 256 + threadIdx.x;  // < 3*2*256*256
    const int n = idx & 255;
    const int kin = (idx >> 8) & 255;
    const int w = (idx >> 16) & 1;
    const int g = idx >> 17;
    const float* W = (g == 0) ? Wz : (g == 1) ? Wf : Wo;
    const float v = W[(size_t)w * 65536 + (size_t)kin * 256 + n];
    Wt[((size_t)g * 256 + n) * 512 + w * 256 + kin] = (_Float16)v;
}

// ---------------------------------------------------------------------------
// MFMA GEMM, counted-vmcnt pipeline (T3/T4): 3 LDS slots, ONE barrier per
// K-step, stage for step t+2 issued right after the barrier of step t, and
// s_waitcnt vmcnt(4) (counted, never 0 in the loop) so prefetch loads stay
// in flight across barriers.  LDS tiles are XOR chunk-swizzled (T2): dest of
// global_load_lds stays linear, the SOURCE chunk is pre-swizzled, and the
// ds_read applies the same swizzle -> bank-uniform ds_read_b128.
// 128x128 tile, 4 waves, 4x4 frags of mfma_f32_16x16x32_f16, BK=32.
// ---------------------------------------------------------------------------
__global__ __launch_bounds__(256) void gates_mfma(
    const _Float16* __restrict__ xpad, const _Float16* __restrict__ Wt,
    const float* __restrict__ bz, const float* __restrict__ bfv,
    const float* __restrict__ bo,
    _Float16* __restrict__ zbuf, _Float16* __restrict__ fbuf,
    _Float16* __restrict__ obuf) {
    const int gate = blockIdx.z;
    const int m0 = blockIdx.x * 128;
    const int n0 = blockIdx.y * 128;
    const int tid = threadIdx.x;
    const int lane = tid & 63;
    const int wave = tid >> 6;
    const int wr = wave >> 1;  // wave row (0..1)
    const int wc = wave & 1;   // wave col (0..1)

    // 3 staging slots of 16 KiB (A 8K | B 8K) = 48 KiB -> 3 blocks/CU.
    // Epilogue reuses [0, 36864) as 4 x 9216 B per-wave repack tiles.
    __shared__ __align__(16) char smem[49152];

    // Staging: segment s covers LDS row s>>2 (16 rows/instr), chunk pos s&3.
    // Linear LDS dest position (row, cpos) must hold global chunk
    // q = cpos ^ ((row>>1)&3); with row = .. + (s>>2), (row>>1)&3 == (s>>3)&3.
    const int s = wave * 64 + lane;
    const int r1 = s >> 2;
    const int kc = (((s & 3) ^ ((s >> 3) & 3))) * 8;  // swizzled src chunk, halves

    const int b = m0 >> 12;
    const int t0 = m0 & (TDIM - 1);

    const _Float16* srcA1 =
        xpad + ((size_t)b * (TDIM + 1) + t0 + r1) * DDIM + kc;
    const _Float16* srcA2 = srcA1 + (size_t)64 * DDIM;
    const _Float16* srcB1 = Wt + ((size_t)gate * 256 + n0 + r1) * 512 + kc;
    const _Float16* srcB2 = srcB1 + (size_t)64 * 512;

#define STAGE_(slot, t)                                                      \
    {                                                                        \
        char* dA = smem + (slot) * 16384 + wave * 1024;                      \
        char* dB = smem + (slot) * 16384 + 8192 + wave * 1024;               \
        GLOAD_LDS16(srcA1 + (t) * 32, dA);                                   \
        GLOAD_LDS16(srcA2 + (t) * 32, dA + 4096);                            \
        GLOAD_LDS16(srcB1 + (t) * 32, dB);                                   \
        GLOAD_LDS16(srcB2 + (t) * 32, dB + 4096);                            \
    }

    f32x4 acc[4][4] = {};
    const int am = lane & 15;
    // Read-side swizzle: chunk c = lane>>4, row&7 == am&7 for every frag,
    // so cpos = c ^ ((am>>1)&3) is a per-lane constant.
    const int kswz = (((lane >> 4) ^ ((lane >> 1) & 3))) * 8;  // halves

    // Prologue: stage K-steps 0 and 1 into slots 0 and 1 (8 loads in flight).
    STAGE_(0, 0);
    STAGE_(1, 1);

#pragma unroll
    for (int it = 0; it < 16; ++it) {
        // Wait for slot it%3's 4 loads; keep the next step's 4 in flight.
        if (it < 15)
            asm volatile("s_waitcnt vmcnt(4)" ::: "memory");
        else
            asm volatile("s_waitcnt vmcnt(0)" ::: "memory");
        __builtin_amdgcn_s_barrier();
        __builtin_amdgcn_sched_barrier(0);
        // All reads of slot (it+2)%3 (done in iter it-1) completed before the
        // barrier above -> safe to overwrite it with K-step it+2 now.  Loads
        // get ~2 full iterations of cover before their vmcnt wait.
        if (it < 14) STAGE_((it + 2) % 3, it + 2);
        __builtin_amdgcn_sched_barrier(0);

        const _Float16* Ab = (const _Float16*)(smem + (it % 3) * 16384);
        const _Float16* Bb = (const _Float16*)(smem + (it % 3) * 16384 + 8192);

        f16x8 a[4], bb[4];
#pragma unroll
        for (int i = 0; i < 4; ++i)
            a[i] = *(const f16x8*)(Ab + (wr * 64 + i * 16 + am) * 32 + kswz);
#pragma unroll
        for (int j = 0; j < 4; ++j)
            bb[j] = *(const f16x8*)(Bb + (wc * 64 + j * 16 + am) * 32 + kswz);

        asm volatile("s_waitcnt lgkmcnt(0)" ::: "memory");
        __builtin_amdgcn_sched_barrier(0);
        __builtin_amdgcn_s_setprio(1);
#pragma unroll
        for (int i = 0; i < 4; ++i)
#pragma unroll
            for (int j = 0; j < 4; ++j)
                acc[i][j] = __builtin_amdgcn_mfma_f32_16x16x32_f16(
                    a[i], bb[j], acc[i][j], 0, 0, 0);
        __builtin_amdgcn_s_setprio(0);
        __builtin_amdgcn_sched_barrier(0);
    }
#undef STAGE_

    __syncthreads();  // all K-loop LDS reads done before epilogue reuse

    // Epilogue: activation into per-wave LDS tile (stride 72 halves = 144 B,
    // 16B-aligned rows; 72 splits the rq-group bank aliasing that stride 80
    // had), then 16 B/lane contiguous global stores.
    const float* bias = (gate == 0) ? bz : (gate == 1) ? bfv : bo;
    _Float16* outp = (gate == 0) ? zbuf : (gate == 1) ? fbuf : obuf;
    _Float16* eb = (_Float16*)smem + wave * 4608;  // 64 x 72 halves
    const int rq = (lane >> 4) * 4;
#pragma unroll
    for (int j = 0; j < 4; ++j) {
        const int gc = n0 + wc * 64 + j * 16 + am;
        const float bj = bias[gc];
#pragma unroll
        for (int i = 0; i < 4; ++i) {
            f32x4 v = acc[i][j];
#pragma unroll
            for (int r = 0; r < 4; ++r) {
                const float val = v[r] + bj;
                const float act = (gate == 0) ? tanh_(val) : sigmoid_(val);
                eb[(i * 16 + rq + r) * 72 + j * 16 + am] = (_Float16)act;
            }
        }
    }
    __syncthreads();  // wave-internal + uniform; ensures writes visible

    const int rrow = lane >> 3;       // 0..7
    const int rcol = (lane & 7) * 8;  // halves
#pragma unroll
    for (int rr = 0; rr < 8; ++rr) {
        const int row = rr * 8 + rrow;
        f16x8 v = *(const f16x8*)(eb + row * 72 + rcol);
        const size_t gm = (size_t)(m0 + wr * 64 + row);
        *(f16x8*)(outp + gm * DDIM + n0 + wc * 64 + rcol) = v;
    }
}

// ---------------------------------------------------------------------------
// Scan pass 1: per-chunk aggregates over LCHUNK steps from c=0; A = prod(f).
// ---------------------------------------------------------------------------
__global__ __launch_bounds__(256) void scan_pass1(
    const _Float16* __restrict__ zbuf, const _Float16* __restrict__ fbuf,
    float* __restrict__ aggA, float* __restrict__ aggB) {
    const int idx = blockIdx.x * 256 + threadIdx.x;  // < B*NCHUNK*32 = 65536
    const int d8 = idx & 31;
    const int chunk = (idx >> 5) & (NCHUNK - 1);
    const int b = idx >> 13;

    const size_t row0 = (size_t)b * TDIM + (size_t)chunk * LCHUNK;
    const int4* zp = (const int4*)zbuf + row0 * 32 + d8;
    const int4* fp = (const int4*)fbuf + row0 * 32 + d8;

    float A[8], c[8];
#pragma unroll
    for (int e = 0; e < 8; ++e) { A[e] = 1.0f; c[e] = 0.0f; }

    for (int i = 0; i < LCHUNK; ++i) {
        int4 fv = *fp;
        int4 zv = *zp;
        const _Float16* fh = (const _Float16*)&fv;
        const _Float16* zh = (const _Float16*)&zv;
#pragma unroll
        for (int e = 0; e < 8; ++e) {
            const float f = (float)fh[e];
            const float z = (float)zh[e];
            A[e] *= f;
            c[e] = f * c[e] + (1.0f - f) * z;
        }
        fp += 32;
        zp += 32;
    }
    ((float4*)aggA)[(size_t)idx * 2 + 0] = make_float4(A[0], A[1], A[2], A[3]);
    ((float4*)aggA)[(size_t)idx * 2 + 1] = make_float4(A[4], A[5], A[6], A[7]);
    ((float4*)aggB)[(size_t)idx * 2 + 0] = make_float4(c[0], c[1], c[2], c[3]);
    ((float4*)aggB)[(size_t)idx * 2 + 1] = make_float4(c[4], c[5], c[6], c[7]);
}

// ---------------------------------------------------------------------------
// Carry scan across chunks: one thread per (b,d) = 2048 threads.
// ---------------------------------------------------------------------------
__global__ __launch_bounds__(256) void carry_scan(
    const float* __restrict__ aggA, const float* __restrict__ aggB,
    float* __restrict__ carry) {
    const int g = blockIdx.x * 256 + threadIdx.x;  // < B*D = 2048
    const int d = g & 255;
    const int b = g >> 8;
    const size_t base = (size_t)b * NCHUNK * 256 + d;

    float c = 0.0f;
    for (int ch0 = 0; ch0 < NCHUNK; ch0 += 8) {
        float A[8], Bv[8];
#pragma unroll
        for (int u = 0; u < 8; ++u) {
            const size_t p = base + (size_t)(ch0 + u) * 256;
            A[u] = aggA[p];
            Bv[u] = aggB[p];
        }
#pragma unroll
        for (int u = 0; u < 8; ++u) {
            const size_t p = base + (size_t)(ch0 + u) * 256;
            carry[p] = c;
            c = A[u] * c + Bv[u];
        }
    }
}

// ---------------------------------------------------------------------------
// Scan pass 2: replay chunk with true carry; h = o*c -> fp32 out.
// ---------------------------------------------------------------------------
__global__ __launch_bounds__(256) void scan_pass2(
    const _Float16* __restrict__ zbuf, const _Float16* __restrict__ fbuf,
    const _Float16* __restrict__ obuf, const float* __restrict__ carry,
    float* __restrict__ out) {
    const int idx = blockIdx.x * 256 + threadIdx.x;  // < 65536
    const int d8 = idx & 31;
    const int chunk = (idx >> 5) & (NCHUNK - 1);
    const int b = idx >> 13;

    float c[8];
    float4 c0 = ((const float4*)carry)[(size_t)idx * 2];
    float4 c1 = ((const float4*)carry)[(size_t)idx * 2 + 1];
    c[0] = c0.x; c[1] = c0.y; c[2] = c0.z; c[3] = c0.w;
    c[4] = c1.x; c[5] = c1.y; c[6] = c1.z; c[7] = c1.w;

    const size_t row0 = (size_t)b * TDIM + (size_t)chunk * LCHUNK;
    const int4* zp = (const int4*)zbuf + row0 * 32 + d8;
    const int4* fp = (const int4*)fbuf + row0 * 32 + d8;
    const int4* op = (const int4*)obuf + row0 * 32 + d8;
    float4* hp = (float4*)out + row0 * 64 + d8 * 2;

    for (int i = 0; i < LCHUNK; ++i) {
        int4 fv = *fp;
        int4 zv = *zp;
        int4 ov = *op;
        const _Float16* fh = (const _Float16*)&fv;
        const _Float16* zh = (const _Float16*)&zv;
        const _Float16* oh = (const _Float16*)&ov;
        float h[8];
#pragma unroll
        for (int e = 0; e < 8; ++e) {
            const float f = (float)fh[e];
            const float z = (float)zh[e];
            c[e] = f * c[e] + (1.0f - f) * z;
            h[e] = (float)oh[e] * c[e];
        }
        hp[0] = make_float4(h[0], h[1], h[2], h[3]);
        hp[1] = make_float4(h[4], h[5], h[6], h[7]);
        fp += 32;
        zp += 32;
        op += 32;
        hp += 64;
    }
}

extern "C" void kernel_launch(void* const* d_in, const int* in_sizes, int n_in,
                              void* d_out, int out_size, void* d_ws,
                              size_t ws_size, hipStream_t stream) {
    const float* x = (const float*)d_in[0];
    const float* Wz = (const float*)d_in[1];
    const float* Wf = (const float*)d_in[2];
    const float* Wo = (const float*)d_in[3];
    const float* bz = (const float*)d_in[4];
    const float* bfv = (const float*)d_in[5];
    const float* bo = (const float*)d_in[6];
    float* out = (float*)d_out;

    // Workspace (bytes): xpad 16.78M | Wt 0.79M | z 16.78M | f 16.78M |
    // o 16.78M | aggA 2M | aggB 2M | carry 2M   -> ~74.7 MB
    char* p = (char*)d_ws;
    _Float16* xpad = (_Float16*)p;  p += (size_t)BDIM * (TDIM + 1) * DDIM * 2;
    _Float16* Wt = (_Float16*)p;    p += (size_t)3 * 256 * 512 * 2;
    _Float16* zbuf = (_Float16*)p;  p += (size_t)MDIM * DDIM * 2;
    _Float16* fbuf = (_Float16*)p;  p += (size_t)MDIM * DDIM * 2;
    _Float16* obuf = (_Float16*)p;  p += (size_t)MDIM * DDIM * 2;
    float* aggA = (float*)p;        p += (size_t)BDIM * NCHUNK * DDIM * 4;
    float* aggB = (float*)p;        p += (size_t)BDIM * NCHUNK * DDIM * 4;
    float* carry = (float*)p;

    convert_x<<<dim3(TDIM + 1, BDIM), 64, 0, stream>>>(x, xpad);
    convert_w<<<(3 * 2 * 256 * 256) / 256, 256, 0, stream>>>(Wz, Wf, Wo, Wt);

    gates_mfma<<<dim3(MDIM / 128, DDIM / 128, 3), 256, 0, stream>>>(
        xpad, Wt, bz, bfv, bo, zbuf, fbuf, obuf);

    scan_pass1<<<(BDIM * NCHUNK * 32) / 256, 256, 0, stream>>>(zbuf, fbuf,
                                                               aggA, aggB);
    carry_scan<<<(BDIM * DDIM) / 256, 256, 0, stream>>>(aggA, aggB, carry);
    scan_pass2<<<(BDIM * NCHUNK * 32) / 256, 256, 0, stream>>>(zbuf, fbuf,
                                                               obuf, carry, out);
}

// Round 2
// 171.024 us; speedup vs baseline: 1.0309x; 1.0139x over previous
//
#include <hip/hip_runtime.h>
#include <hip/hip_bf16.h>
#include <hip/hip_fp16.h>

// Problem constants (B=8, T=4096, Din=Dout=256, WINDOW=2)
#define BDIM 8
#define TDIM 4096
#define DDIM 256
#define MDIM (BDIM * TDIM)      // 32768
#define NCHUNK 256              // chunks along T for the parallel scan
#define LCHUNK (TDIM / NCHUNK)  // 16

typedef _Float16 f16x8 __attribute__((ext_vector_type(8)));
typedef _Float16 f16x4 __attribute__((ext_vector_type(4)));
typedef float f32x4 __attribute__((ext_vector_type(4)));

__device__ __forceinline__ float sigmoid_(float x) {
    return 1.0f / (1.0f + __expf(-x));
}
__device__ __forceinline__ float tanh_(float x) {
    return 2.0f / (1.0f + __expf(-2.0f * x)) - 1.0f;
}

#define GLOAD_LDS16(g, l)                                                    \
    __builtin_amdgcn_global_load_lds(                                        \
        (const __attribute__((address_space(1))) void*)(g),                  \
        (__attribute__((address_space(3))) void*)(l), 16, 0, 0)

// ---------------------------------------------------------------------------
// x [B,T,D] fp32 -> xpad [B,T+1,D] f16 with a zero row at t'=0.
// 256-thread blocks, 4 rows each (fewer, fatter blocks than 1-wave version).
// ---------------------------------------------------------------------------
__global__ __launch_bounds__(256) void convert_x(const float* __restrict__ x,
                                                 _Float16* __restrict__ xpad) {
    const int tp = blockIdx.x * 4 + (threadIdx.x >> 6);  // padded row
    const int b = blockIdx.y;
    const int q = threadIdx.x & 63;  // 4 floats each
    if (tp > TDIM) return;
    float4 v = make_float4(0.f, 0.f, 0.f, 0.f);
    if (tp > 0)
        v = *(const float4*)(x + ((size_t)b * TDIM + tp - 1) * DDIM + q * 4);
    f16x4 h;
    h[0] = (_Float16)v.x; h[1] = (_Float16)v.y;
    h[2] = (_Float16)v.z; h[3] = (_Float16)v.w;
    *(f16x4*)(xpad + ((size_t)b * (TDIM + 1) + tp) * DDIM + q * 4) = h;
}

// ---------------------------------------------------------------------------
// W[g][w][kin][n] fp32 -> Wt[g][n][w*256+kin] f16 (contiguous in k).
// ---------------------------------------------------------------------------
__global__ __launch_bounds__(256) void convert_w(
    const float* __restrict__ Wz, const float* __restrict__ Wf,
    const float* __restrict__ Wo, _Float16* __restrict__ Wt) {
    const int idx = blockIdx.x * 256 + threadIdx.x;  // < 3*2*256*256
    const int n = idx & 255;
    const int kin = (idx >> 8) & 255;
    const int w = (idx >> 16) & 1;
    const int g = idx >> 17;
    const float* W = (g == 0) ? Wz : (g == 1) ? Wf : Wo;
    const float v = W[(size_t)w * 65536 + (size_t)kin * 256 + n];
    Wt[((size_t)g * 256 + n) * 512 + w * 256 + kin] = (_Float16)v;
}

// ---------------------------------------------------------------------------
// MFMA GEMM, counted-vmcnt pipeline (T3/T4): 3 LDS slots, ONE barrier per
// K-step, stage for step t+2 issued right after the barrier of step t,
// s_waitcnt vmcnt(4) (counted, never 0 mid-loop).  LDS XOR chunk-swizzled
// (T2): linear gload_lds dest, pre-swizzled global source, swizzled ds_read.
// Epilogue: MFMA operands SWAPPED (mfma(b,a) -> C^T fragment layout), so each
// lane's f32x4 acc = 4 consecutive output COLUMNS at one row -> activation +
// one f16x4 (8 B) global store per frag.  No epilogue LDS round-trip.
// ---------------------------------------------------------------------------
__global__ __launch_bounds__(256) void gates_mfma(
    const _Float16* __restrict__ xpad, const _Float16* __restrict__ Wt,
    const float* __restrict__ bz, const float* __restrict__ bfv,
    const float* __restrict__ bo,
    _Float16* __restrict__ zbuf, _Float16* __restrict__ fbuf,
    _Float16* __restrict__ obuf) {
    const int gate = blockIdx.z;
    const int m0 = blockIdx.x * 128;
    const int n0 = blockIdx.y * 128;
    const int tid = threadIdx.x;
    const int lane = tid & 63;
    const int wave = tid >> 6;
    const int wr = wave >> 1;  // wave row (0..1)
    const int wc = wave & 1;   // wave col (0..1)

    // 3 staging slots of 16 KiB (A 8K | B 8K) = 48 KiB -> 3 blocks/CU.
    __shared__ __align__(16) char smem[49152];

    // Staging: segment s covers LDS row s>>2, chunk pos s&3; linear dest
    // position (row, cpos) holds global chunk cpos ^ ((row>>1)&3).
    const int s = wave * 64 + lane;
    const int r1 = s >> 2;
    const int kc = (((s & 3) ^ ((s >> 3) & 3))) * 8;  // swizzled src chunk

    const int b = m0 >> 12;
    const int t0 = m0 & (TDIM - 1);

    const _Float16* srcA1 =
        xpad + ((size_t)b * (TDIM + 1) + t0 + r1) * DDIM + kc;
    const _Float16* srcA2 = srcA1 + (size_t)64 * DDIM;
    const _Float16* srcB1 = Wt + ((size_t)gate * 256 + n0 + r1) * 512 + kc;
    const _Float16* srcB2 = srcB1 + (size_t)64 * 512;

#define STAGE_(slot, t)                                                      \
    {                                                                        \
        char* dA = smem + (slot) * 16384 + wave * 1024;                      \
        char* dB = smem + (slot) * 16384 + 8192 + wave * 1024;               \
        GLOAD_LDS16(srcA1 + (t) * 32, dA);                                   \
        GLOAD_LDS16(srcA2 + (t) * 32, dA + 4096);                            \
        GLOAD_LDS16(srcB1 + (t) * 32, dB);                                   \
        GLOAD_LDS16(srcB2 + (t) * 32, dB + 4096);                            \
    }

    f32x4 acc[4][4] = {};
    const int am = lane & 15;
    // Read-side swizzle: chunk c = lane>>4, cpos = c ^ ((am>>1)&3).
    const int kswz = (((lane >> 4) ^ ((lane >> 1) & 3))) * 8;  // halves

    // Prologue: stage K-steps 0 and 1 into slots 0 and 1 (8 loads in flight).
    STAGE_(0, 0);
    STAGE_(1, 1);

#pragma unroll
    for (int it = 0; it < 16; ++it) {
        // Wait for slot it%3's 4 loads; keep the next step's 4 in flight.
        if (it < 15)
            asm volatile("s_waitcnt vmcnt(4)" ::: "memory");
        else
            asm volatile("s_waitcnt vmcnt(0)" ::: "memory");
        __builtin_amdgcn_s_barrier();
        __builtin_amdgcn_sched_barrier(0);
        // Slot (it+2)%3's reads finished in iter it-1 (before the barrier
        // above) -> safe to overwrite with K-step it+2 now.
        if (it < 14) STAGE_((it + 2) % 3, it + 2);
        __builtin_amdgcn_sched_barrier(0);

        const _Float16* Ab = (const _Float16*)(smem + (it % 3) * 16384);
        const _Float16* Bb = (const _Float16*)(smem + (it % 3) * 16384 + 8192);

        f16x8 a[4], bb[4];
#pragma unroll
        for (int i = 0; i < 4; ++i)
            a[i] = *(const f16x8*)(Ab + (wr * 64 + i * 16 + am) * 32 + kswz);
#pragma unroll
        for (int j = 0; j < 4; ++j)
            bb[j] = *(const f16x8*)(Bb + (wc * 64 + j * 16 + am) * 32 + kswz);

        asm volatile("s_waitcnt lgkmcnt(0)" ::: "memory");
        __builtin_amdgcn_sched_barrier(0);
        __builtin_amdgcn_s_setprio(1);
        // SWAPPED operands: D = bb^T-space x a-space -> per lane, acc[i][j]
        // reg r = C[m][n] with m = i*16 + (lane&15), n = j*16+(lane>>4)*4+r.
#pragma unroll
        for (int i = 0; i < 4; ++i)
#pragma unroll
            for (int j = 0; j < 4; ++j)
                acc[i][j] = __builtin_amdgcn_mfma_f32_16x16x32_f16(
                    bb[j], a[i], acc[i][j], 0, 0, 0);
        __builtin_amdgcn_s_setprio(0);
        __builtin_amdgcn_sched_barrier(0);
    }
#undef STAGE_

    // Epilogue: per (i,j) frag = 4 consecutive columns at one row.
    // float4 bias load, activation, one 8-B f16x4 store. No LDS, no barrier.
    const float* bias = (gate == 0) ? bz : (gate == 1) ? bfv : bo;
    _Float16* outp = (gate == 0) ? zbuf : (gate == 1) ? fbuf : obuf;
    const int nq = (lane >> 4) * 4;  // n within 16-frag (4 consecutive)
#pragma unroll
    for (int i = 0; i < 4; ++i) {
        const size_t gm = (size_t)(m0 + wr * 64 + i * 16 + am);
#pragma unroll
        for (int j = 0; j < 4; ++j) {
            const int gc = n0 + wc * 64 + j * 16 + nq;
            const float4 b4 = *(const float4*)(bias + gc);
            f32x4 v = acc[i][j];
            f16x4 h;
            if (gate == 0) {
                h[0] = (_Float16)tanh_(v[0] + b4.x);
                h[1] = (_Float16)tanh_(v[1] + b4.y);
                h[2] = (_Float16)tanh_(v[2] + b4.z);
                h[3] = (_Float16)tanh_(v[3] + b4.w);
            } else {
                h[0] = (_Float16)sigmoid_(v[0] + b4.x);
                h[1] = (_Float16)sigmoid_(v[1] + b4.y);
                h[2] = (_Float16)sigmoid_(v[2] + b4.z);
                h[3] = (_Float16)sigmoid_(v[3] + b4.w);
            }
            *(f16x4*)(outp + gm * DDIM + gc) = h;
        }
    }
}

// ---------------------------------------------------------------------------
// Scan pass 1: per-chunk aggregates over LCHUNK steps from c=0; A = prod(f).
// 4 channels/thread -> 131072 threads (2 waves/SIMD) for latency hiding.
// ---------------------------------------------------------------------------
__global__ __launch_bounds__(256) void scan_pass1(
    const _Float16* __restrict__ zbuf, const _Float16* __restrict__ fbuf,
    float* __restrict__ aggA, float* __restrict__ aggB) {
    const int idx = blockIdx.x * 256 + threadIdx.x;  // < B*NCHUNK*64 = 131072
    const int d4 = idx & 63;
    const int chunk = (idx >> 6) & (NCHUNK - 1);
    const int b = idx >> 14;

    const size_t row0 = (size_t)b * TDIM + (size_t)chunk * LCHUNK;
    const int2* zp = (const int2*)zbuf + row0 * 64 + d4;
    const int2* fp = (const int2*)fbuf + row0 * 64 + d4;

    float A[4], c[4];
#pragma unroll
    for (int e = 0; e < 4; ++e) { A[e] = 1.0f; c[e] = 0.0f; }

    for (int i = 0; i < LCHUNK; ++i) {
        int2 fv = *fp;
        int2 zv = *zp;
        const _Float16* fh = (const _Float16*)&fv;
        const _Float16* zh = (const _Float16*)&zv;
#pragma unroll
        for (int e = 0; e < 4; ++e) {
            const float f = (float)fh[e];
            const float z = (float)zh[e];
            A[e] *= f;
            c[e] = f * c[e] + (1.0f - f) * z;
        }
        fp += 64;
        zp += 64;
    }
    ((float4*)aggA)[idx] = make_float4(A[0], A[1], A[2], A[3]);
    ((float4*)aggB)[idx] = make_float4(c[0], c[1], c[2], c[3]);
}

// ---------------------------------------------------------------------------
// Carry scan across chunks: one thread per (b,d) = 2048 threads.
// ---------------------------------------------------------------------------
__global__ __launch_bounds__(256) void carry_scan(
    const float* __restrict__ aggA, const float* __restrict__ aggB,
    float* __restrict__ carry) {
    const int g = blockIdx.x * 256 + threadIdx.x;  // < B*D = 2048
    const int d = g & 255;
    const int b = g >> 8;
    const size_t base = (size_t)b * NCHUNK * 256 + d;

    float c = 0.0f;
    for (int ch0 = 0; ch0 < NCHUNK; ch0 += 8) {
        float A[8], Bv[8];
#pragma unroll
        for (int u = 0; u < 8; ++u) {
            const size_t p = base + (size_t)(ch0 + u) * 256;
            A[u] = aggA[p];
            Bv[u] = aggB[p];
        }
#pragma unroll
        for (int u = 0; u < 8; ++u) {
            const size_t p = base + (size_t)(ch0 + u) * 256;
            carry[p] = c;
            c = A[u] * c + Bv[u];
        }
    }
}

// ---------------------------------------------------------------------------
// Scan pass 2: replay chunk with true carry; h = o*c -> fp32 out.
// 4 channels/thread -> 131072 threads; one float4 store per step.
// ---------------------------------------------------------------------------
__global__ __launch_bounds__(256) void scan_pass2(
    const _Float16* __restrict__ zbuf, const _Float16* __restrict__ fbuf,
    const _Float16* __restrict__ obuf, const float* __restrict__ carry,
    float* __restrict__ out) {
    const int idx = blockIdx.x * 256 + threadIdx.x;  // < 131072
    const int d4 = idx & 63;
    const int chunk = (idx >> 6) & (NCHUNK - 1);
    const int b = idx >> 14;

    float c[4];
    const float4 c0 = ((const float4*)carry)[idx];
    c[0] = c0.x; c[1] = c0.y; c[2] = c0.z; c[3] = c0.w;

    const size_t row0 = (size_t)b * TDIM + (size_t)chunk * LCHUNK;
    const int2* zp = (const int2*)zbuf + row0 * 64 + d4;
    const int2* fp = (const int2*)fbuf + row0 * 64 + d4;
    const int2* op = (const int2*)obuf + row0 * 64 + d4;
    float4* hp = (float4*)out + row0 * 64 + d4;

    for (int i = 0; i < LCHUNK; ++i) {
        int2 fv = *fp;
        int2 zv = *zp;
        int2 ov = *op;
        const _Float16* fh = (const _Float16*)&fv;
        const _Float16* zh = (const _Float16*)&zv;
        const _Float16* oh = (const _Float16*)&ov;
        float h[4];
#pragma unroll
        for (int e = 0; e < 4; ++e) {
            const float f = (float)fh[e];
            const float z = (float)zh[e];
            c[e] = f * c[e] + (1.0f - f) * z;
            h[e] = (float)oh[e] * c[e];
        }
        *hp = make_float4(h[0], h[1], h[2], h[3]);
        fp += 64;
        zp += 64;
        op += 64;
        hp += 64;
    }
}

extern "C" void kernel_launch(void* const* d_in, const int* in_sizes, int n_in,
                              void* d_out, int out_size, void* d_ws,
                              size_t ws_size, hipStream_t stream) {
    const float* x = (const float*)d_in[0];
    const float* Wz = (const float*)d_in[1];
    const float* Wf = (const float*)d_in[2];
    const float* Wo = (const float*)d_in[3];
    const float* bz = (const float*)d_in[4];
    const float* bfv = (const float*)d_in[5];
    const float* bo = (const float*)d_in[6];
    float* out = (float*)d_out;

    // Workspace (bytes): xpad 16.78M | Wt 0.79M | z 16.78M | f 16.78M |
    // o 16.78M | aggA 2M | aggB 2M | carry 2M   -> ~74.7 MB
    char* p = (char*)d_ws;
    _Float16* xpad = (_Float16*)p;  p += (size_t)BDIM * (TDIM + 1) * DDIM * 2;
    _Float16* Wt = (_Float16*)p;    p += (size_t)3 * 256 * 512 * 2;
    _Float16* zbuf = (_Float16*)p;  p += (size_t)MDIM * DDIM * 2;
    _Float16* fbuf = (_Float16*)p;  p += (size_t)MDIM * DDIM * 2;
    _Float16* obuf = (_Float16*)p;  p += (size_t)MDIM * DDIM * 2;
    float* aggA = (float*)p;        p += (size_t)BDIM * NCHUNK * DDIM * 4;
    float* aggB = (float*)p;        p += (size_t)BDIM * NCHUNK * DDIM * 4;
    float* carry = (float*)p;

    convert_x<<<dim3((TDIM + 4) / 4, BDIM), 256, 0, stream>>>(x, xpad);
    convert_w<<<(3 * 2 * 256 * 256) / 256, 256, 0, stream>>>(Wz, Wf, Wo, Wt);

    gates_mfma<<<dim3(MDIM / 128, DDIM / 128, 3), 256, 0, stream>>>(
        xpad, Wt, bz, bfv, bo, zbuf, fbuf, obuf);

    scan_pass1<<<(BDIM * NCHUNK * 64) / 256, 256, 0, stream>>>(zbuf, fbuf,
                                                               aggA, aggB);
    carry_scan<<<(BDIM * DDIM) / 256, 256, 0, stream>>>(aggA, aggB, carry);
    scan_pass2<<<(BDIM * NCHUNK * 64) / 256, 256, 0, stream>>>(zbuf, fbuf,
                                                               obuf, carry, out);
}

// Round 3
// 166.293 us; speedup vs baseline: 1.0603x; 1.0284x over previous
//
#include <hip/hip_runtime.h>
#include <hip/hip_bf16.h>
#include <hip/hip_fp16.h>

// Problem constants (B=8, T=4096, Din=Dout=256, WINDOW=2)
#define BDIM 8
#define TDIM 4096
#define DDIM 256
#define MDIM (BDIM * TDIM)      // 32768
#define NCHUNK 256              // chunks along T for the parallel scan
#define LCHUNK (TDIM / NCHUNK)  // 16

typedef _Float16 f16x8 __attribute__((ext_vector_type(8)));
typedef _Float16 f16x4 __attribute__((ext_vector_type(4)));
typedef float f32x4 __attribute__((ext_vector_type(4)));

__device__ __forceinline__ float sigmoid_(float x) {
    return 1.0f / (1.0f + __expf(-x));
}
__device__ __forceinline__ float tanh_(float x) {
    return 2.0f / (1.0f + __expf(-2.0f * x)) - 1.0f;
}

#define GLOAD_LDS16(g, l)                                                    \
    __builtin_amdgcn_global_load_lds(                                        \
        (const __attribute__((address_space(1))) void*)(g),                  \
        (__attribute__((address_space(3))) void*)(l), 16, 0, 0)

// ---------------------------------------------------------------------------
// x [B,T,D] fp32 -> xpad [B,T+1,D] f16 with a zero row at t'=0.
// ---------------------------------------------------------------------------
__global__ __launch_bounds__(256) void convert_x(const float* __restrict__ x,
                                                 _Float16* __restrict__ xpad) {
    const int tp = blockIdx.x * 4 + (threadIdx.x >> 6);  // padded row
    const int b = blockIdx.y;
    const int q = threadIdx.x & 63;  // 4 floats each
    if (tp > TDIM) return;
    float4 v = make_float4(0.f, 0.f, 0.f, 0.f);
    if (tp > 0)
        v = *(const float4*)(x + ((size_t)b * TDIM + tp - 1) * DDIM + q * 4);
    f16x4 h;
    h[0] = (_Float16)v.x; h[1] = (_Float16)v.y;
    h[2] = (_Float16)v.z; h[3] = (_Float16)v.w;
    *(f16x4*)(xpad + ((size_t)b * (TDIM + 1) + tp) * DDIM + q * 4) = h;
}

// ---------------------------------------------------------------------------
// W[g][w][kin][n] fp32 -> Wt[g][n][w*256+kin] f16 (contiguous in k).
// ---------------------------------------------------------------------------
__global__ __launch_bounds__(256) void convert_w(
    const float* __restrict__ Wz, const float* __restrict__ Wf,
    const float* __restrict__ Wo, _Float16* __restrict__ Wt) {
    const int idx = blockIdx.x * 256 + threadIdx.x;  // < 3*2*256*256
    const int n = idx & 255;
    const int kin = (idx >> 8) & 255;
    const int w = (idx >> 16) & 1;
    const int g = idx >> 17;
    const float* W = (g == 0) ? Wz : (g == 1) ? Wf : Wo;
    const float v = W[(size_t)w * 65536 + (size_t)kin * 256 + n];
    Wt[((size_t)g * 256 + n) * 512 + w * 256 + kin] = (_Float16)v;
}

// ---------------------------------------------------------------------------
// MFMA GEMM.  4-slot LDS ring, counted-vmcnt pipeline: stage for K-step t+3
// issued at iter t, steady-state s_waitcnt vmcnt(8) -> each load gets ~3
// iterations of cover (enough for L3-miss latency).  XCD-aware 1-D grid
// swizzle with (n,gate) INNERMOST so the 6 blocks sharing an A-tile run
// back-to-back on one XCD (A-tile L2-hot; Wt 768 KB always L2-hot).
// LDS XOR chunk-swizzled (T2): linear gload_lds dest, pre-swizzled global
// source, swizzled ds_read -> zero bank conflicts (verified R2).
// Epilogue: swapped-operand MFMA layout -> direct f16x4 stores, no LDS.
// ---------------------------------------------------------------------------
__global__ __launch_bounds__(256) void gates_mfma(
    const _Float16* __restrict__ xpad, const _Float16* __restrict__ Wt,
    const float* __restrict__ bz, const float* __restrict__ bfv,
    const float* __restrict__ bo,
    _Float16* __restrict__ zbuf, _Float16* __restrict__ fbuf,
    _Float16* __restrict__ obuf) {
    // XCD swizzle: 1536 blocks = 8 XCDs x 192.  hw dispatch round-robins
    // XCDs by index, so hw&7 == XCD; give each XCD a contiguous logical run.
    const int hw = blockIdx.x;
    const int logical = (hw & 7) * 192 + (hw >> 3);
    const int mblk = logical / 6;
    const int rem = logical - mblk * 6;   // (n,gate) innermost: 6 sharers of
    const int gate = rem % 3;             // one A-tile are consecutive.
    const int nblk = rem / 3;
    const int m0 = mblk * 128;
    const int n0 = nblk * 128;

    const int tid = threadIdx.x;
    const int lane = tid & 63;
    const int wave = tid >> 6;
    const int wr = wave >> 1;  // wave row (0..1)
    const int wc = wave & 1;   // wave col (0..1)

    // 4 staging slots of 16 KiB (A 8K | B 8K) = 64 KiB -> 2 blocks/CU.
    __shared__ __align__(16) char smem[65536];

    // Staging: segment s covers LDS row s>>2, chunk pos s&3; linear dest
    // position (row, cpos) holds global chunk cpos ^ ((row>>1)&3).
    const int s = wave * 64 + lane;
    const int r1 = s >> 2;
    const int kc = (((s & 3) ^ ((s >> 3) & 3))) * 8;  // swizzled src chunk

    const int b = m0 >> 12;
    const int t0 = m0 & (TDIM - 1);

    const _Float16* srcA1 =
        xpad + ((size_t)b * (TDIM + 1) + t0 + r1) * DDIM + kc;
    const _Float16* srcA2 = srcA1 + (size_t)64 * DDIM;
    const _Float16* srcB1 = Wt + ((size_t)gate * 256 + n0 + r1) * 512 + kc;
    const _Float16* srcB2 = srcB1 + (size_t)64 * 512;

#define STAGE_(slot, t)                                                      \
    {                                                                        \
        char* dA = smem + (slot) * 16384 + wave * 1024;                      \
        char* dB = smem + (slot) * 16384 + 8192 + wave * 1024;               \
        GLOAD_LDS16(srcA1 + (t) * 32, dA);                                   \
        GLOAD_LDS16(srcA2 + (t) * 32, dA + 4096);                            \
        GLOAD_LDS16(srcB1 + (t) * 32, dB);                                   \
        GLOAD_LDS16(srcB2 + (t) * 32, dB + 4096);                            \
    }

    f32x4 acc[4][4] = {};
    const int am = lane & 15;
    // Read-side swizzle: chunk c = lane>>4, cpos = c ^ ((am>>1)&3).
    const int kswz = (((lane >> 4) ^ ((lane >> 1) & 3))) * 8;  // halves

    // Prologue: stage K-steps 0..2 into slots 0..2 (12 loads in flight).
    STAGE_(0, 0);
    STAGE_(1, 1);
    STAGE_(2, 2);

#pragma unroll
    for (int it = 0; it < 16; ++it) {
        // Drain exactly this iter's slot; keep up to 8 newer loads in flight.
        // Outstanding before wait: 12 (it<=13), 8 (it==14), 4 (it==15).
        if (it <= 13)
            asm volatile("s_waitcnt vmcnt(8)" ::: "memory");
        else if (it == 14)
            asm volatile("s_waitcnt vmcnt(4)" ::: "memory");
        else
            asm volatile("s_waitcnt vmcnt(0)" ::: "memory");
        __builtin_amdgcn_s_barrier();
        __builtin_amdgcn_sched_barrier(0);
        // Slot (it+3)&3 was last read at iter it-1; those ds_reads completed
        // before the barrier above -> safe to overwrite with K-step it+3.
        if (it < 13) STAGE_((it + 3) & 3, it + 3);
        __builtin_amdgcn_sched_barrier(0);

        const _Float16* Ab = (const _Float16*)(smem + (it & 3) * 16384);
        const _Float16* Bb = (const _Float16*)(smem + (it & 3) * 16384 + 8192);

        f16x8 a[4], bb[4];
#pragma unroll
        for (int i = 0; i < 4; ++i)
            a[i] = *(const f16x8*)(Ab + (wr * 64 + i * 16 + am) * 32 + kswz);
#pragma unroll
        for (int j = 0; j < 4; ++j)
            bb[j] = *(const f16x8*)(Bb + (wc * 64 + j * 16 + am) * 32 + kswz);

        asm volatile("s_waitcnt lgkmcnt(0)" ::: "memory");
        __builtin_amdgcn_sched_barrier(0);
        __builtin_amdgcn_s_setprio(1);
        // SWAPPED operands: per lane, acc[i][j] reg r = C[m][n] with
        // m = i*16 + (lane&15), n = j*16 + (lane>>4)*4 + r.
#pragma unroll
        for (int i = 0; i < 4; ++i)
#pragma unroll
            for (int j = 0; j < 4; ++j)
                acc[i][j] = __builtin_amdgcn_mfma_f32_16x16x32_f16(
                    bb[j], a[i], acc[i][j], 0, 0, 0);
        __builtin_amdgcn_s_setprio(0);
        __builtin_amdgcn_sched_barrier(0);
    }
#undef STAGE_

    // Epilogue: per (i,j) frag = 4 consecutive columns at one row.
    // float4 bias load, activation, one 8-B f16x4 store. No LDS, no barrier.
    const float* bias = (gate == 0) ? bz : (gate == 1) ? bfv : bo;
    _Float16* outp = (gate == 0) ? zbuf : (gate == 1) ? fbuf : obuf;
    const int nq = (lane >> 4) * 4;  // n within 16-frag (4 consecutive)
#pragma unroll
    for (int i = 0; i < 4; ++i) {
        const size_t gm = (size_t)(m0 + wr * 64 + i * 16 + am);
#pragma unroll
        for (int j = 0; j < 4; ++j) {
            const int gc = n0 + wc * 64 + j * 16 + nq;
            const float4 b4 = *(const float4*)(bias + gc);
            f32x4 v = acc[i][j];
            f16x4 h;
            if (gate == 0) {
                h[0] = (_Float16)tanh_(v[0] + b4.x);
                h[1] = (_Float16)tanh_(v[1] + b4.y);
                h[2] = (_Float16)tanh_(v[2] + b4.z);
                h[3] = (_Float16)tanh_(v[3] + b4.w);
            } else {
                h[0] = (_Float16)sigmoid_(v[0] + b4.x);
                h[1] = (_Float16)sigmoid_(v[1] + b4.y);
                h[2] = (_Float16)sigmoid_(v[2] + b4.z);
                h[3] = (_Float16)sigmoid_(v[3] + b4.w);
            }
            *(f16x4*)(outp + gm * DDIM + gc) = h;
        }
    }
}

// ---------------------------------------------------------------------------
// Scan pass 1: per-chunk aggregates over LCHUNK steps from c=0; A = prod(f).
// 4 channels/thread -> 131072 threads (2 waves/SIMD) for latency hiding.
// ---------------------------------------------------------------------------
__global__ __launch_bounds__(256) void scan_pass1(
    const _Float16* __restrict__ zbuf, const _Float16* __restrict__ fbuf,
    float* __restrict__ aggA, float* __restrict__ aggB) {
    const int idx = blockIdx.x * 256 + threadIdx.x;  // < B*NCHUNK*64 = 131072
    const int d4 = idx & 63;
    const int chunk = (idx >> 6) & (NCHUNK - 1);
    const int b = idx >> 14;

    const size_t row0 = (size_t)b * TDIM + (size_t)chunk * LCHUNK;
    const int2* zp = (const int2*)zbuf + row0 * 64 + d4;
    const int2* fp = (const int2*)fbuf + row0 * 64 + d4;

    float A[4], c[4];
#pragma unroll
    for (int e = 0; e < 4; ++e) { A[e] = 1.0f; c[e] = 0.0f; }

    for (int i = 0; i < LCHUNK; ++i) {
        int2 fv = *fp;
        int2 zv = *zp;
        const _Float16* fh = (const _Float16*)&fv;
        const _Float16* zh = (const _Float16*)&zv;
#pragma unroll
        for (int e = 0; e < 4; ++e) {
            const float f = (float)fh[e];
            const float z = (float)zh[e];
            A[e] *= f;
            c[e] = f * c[e] + (1.0f - f) * z;
        }
        fp += 64;
        zp += 64;
    }
    ((float4*)aggA)[idx] = make_float4(A[0], A[1], A[2], A[3]);
    ((float4*)aggB)[idx] = make_float4(c[0], c[1], c[2], c[3]);
}

// ---------------------------------------------------------------------------
// Carry scan across chunks: one thread per (b,d) = 2048 threads.
// Unroll-16 batched loads: 16 latency rounds instead of 32.
// ---------------------------------------------------------------------------
__global__ __launch_bounds__(256) void carry_scan(
    const float* __restrict__ aggA, const float* __restrict__ aggB,
    float* __restrict__ carry) {
    const int g = blockIdx.x * 256 + threadIdx.x;  // < B*D = 2048
    const int d = g & 255;
    const int b = g >> 8;
    const size_t base = (size_t)b * NCHUNK * 256 + d;

    float c = 0.0f;
    for (int ch0 = 0; ch0 < NCHUNK; ch0 += 16) {
        float A[16], Bv[16];
#pragma unroll
        for (int u = 0; u < 16; ++u) {
            const size_t p = base + (size_t)(ch0 + u) * 256;
            A[u] = aggA[p];
            Bv[u] = aggB[p];
        }
#pragma unroll
        for (int u = 0; u < 16; ++u) {
            const size_t p = base + (size_t)(ch0 + u) * 256;
            carry[p] = c;
            c = A[u] * c + Bv[u];
        }
    }
}

// ---------------------------------------------------------------------------
// Scan pass 2: replay chunk with true carry; h = o*c -> fp32 out.
// 4 channels/thread -> 131072 threads; one float4 store per step.
// ---------------------------------------------------------------------------
__global__ __launch_bounds__(256) void scan_pass2(
    const _Float16* __restrict__ zbuf, const _Float16* __restrict__ fbuf,
    const _Float16* __restrict__ obuf, const float* __restrict__ carry,
    float* __restrict__ out) {
    const int idx = blockIdx.x * 256 + threadIdx.x;  // < 131072
    const int d4 = idx & 63;
    const int chunk = (idx >> 6) & (NCHUNK - 1);
    const int b = idx >> 14;

    float c[4];
    const float4 c0 = ((const float4*)carry)[idx];
    c[0] = c0.x; c[1] = c0.y; c[2] = c0.z; c[3] = c0.w;

    const size_t row0 = (size_t)b * TDIM + (size_t)chunk * LCHUNK;
    const int2* zp = (const int2*)zbuf + row0 * 64 + d4;
    const int2* fp = (const int2*)fbuf + row0 * 64 + d4;
    const int2* op = (const int2*)obuf + row0 * 64 + d4;
    float4* hp = (float4*)out + row0 * 64 + d4;

    for (int i = 0; i < LCHUNK; ++i) {
        int2 fv = *fp;
        int2 zv = *zp;
        int2 ov = *op;
        const _Float16* fh = (const _Float16*)&fv;
        const _Float16* zh = (const _Float16*)&zv;
        const _Float16* oh = (const _Float16*)&ov;
        float h[4];
#pragma unroll
        for (int e = 0; e < 4; ++e) {
            const float f = (float)fh[e];
            const float z = (float)zh[e];
            c[e] = f * c[e] + (1.0f - f) * z;
            h[e] = (float)oh[e] * c[e];
        }
        *hp = make_float4(h[0], h[1], h[2], h[3]);
        fp += 64;
        zp += 64;
        op += 64;
        hp += 64;
    }
}

extern "C" void kernel_launch(void* const* d_in, const int* in_sizes, int n_in,
                              void* d_out, int out_size, void* d_ws,
                              size_t ws_size, hipStream_t stream) {
    const float* x = (const float*)d_in[0];
    const float* Wz = (const float*)d_in[1];
    const float* Wf = (const float*)d_in[2];
    const float* Wo = (const float*)d_in[3];
    const float* bz = (const float*)d_in[4];
    const float* bfv = (const float*)d_in[5];
    const float* bo = (const float*)d_in[6];
    float* out = (float*)d_out;

    // Workspace (bytes): xpad 16.78M | Wt 0.79M | z 16.78M | f 16.78M |
    // o 16.78M | aggA 2M | aggB 2M | carry 2M   -> ~74.7 MB
    char* p = (char*)d_ws;
    _Float16* xpad = (_Float16*)p;  p += (size_t)BDIM * (TDIM + 1) * DDIM * 2;
    _Float16* Wt = (_Float16*)p;    p += (size_t)3 * 256 * 512 * 2;
    _Float16* zbuf = (_Float16*)p;  p += (size_t)MDIM * DDIM * 2;
    _Float16* fbuf = (_Float16*)p;  p += (size_t)MDIM * DDIM * 2;
    _Float16* obuf = (_Float16*)p;  p += (size_t)MDIM * DDIM * 2;
    float* aggA = (float*)p;        p += (size_t)BDIM * NCHUNK * DDIM * 4;
    float* aggB = (float*)p;        p += (size_t)BDIM * NCHUNK * DDIM * 4;
    float* carry = (float*)p;

    convert_x<<<dim3((TDIM + 4) / 4, BDIM), 256, 0, stream>>>(x, xpad);
    convert_w<<<(3 * 2 * 256 * 256) / 256, 256, 0, stream>>>(Wz, Wf, Wo, Wt);

    gates_mfma<<<MDIM / 128 * (DDIM / 128) * 3, 256, 0, stream>>>(
        xpad, Wt, bz, bfv, bo, zbuf, fbuf, obuf);

    scan_pass1<<<(BDIM * NCHUNK * 64) / 256, 256, 0, stream>>>(zbuf, fbuf,
                                                               aggA, aggB);
    carry_scan<<<(BDIM * DDIM) / 256, 256, 0, stream>>>(aggA, aggB, carry);
    scan_pass2<<<(BDIM * NCHUNK * 64) / 256, 256, 0, stream>>>(zbuf, fbuf,
                                                               obuf, carry, out);
}

// Round 4
// 164.845 us; speedup vs baseline: 1.0696x; 1.0088x over previous
//
#include <hip/hip_runtime.h>
#include <hip/hip_bf16.h>
#include <hip/hip_fp16.h>

// Problem constants (B=8, T=4096, Din=Dout=256, WINDOW=2)
#define BDIM 8
#define TDIM 4096
#define DDIM 256
#define MDIM (BDIM * TDIM)      // 32768
#define NCHUNK 256              // chunks along T for the parallel scan
#define LCHUNK (TDIM / NCHUNK)  // 16

typedef _Float16 f16x8 __attribute__((ext_vector_type(8)));
typedef _Float16 f16x4 __attribute__((ext_vector_type(4)));
typedef float f32x4 __attribute__((ext_vector_type(4)));

__device__ __forceinline__ float sigmoid_(float x) {
    return 1.0f / (1.0f + __expf(-x));
}
__device__ __forceinline__ float tanh_(float x) {
    return 2.0f / (1.0f + __expf(-2.0f * x)) - 1.0f;
}

#define GLOAD_LDS16(g, l)                                                    \
    __builtin_amdgcn_global_load_lds(                                        \
        (const __attribute__((address_space(1))) void*)(g),                  \
        (__attribute__((address_space(3))) void*)(l), 16, 0, 0)

// ---------------------------------------------------------------------------
// Fused prep: blocks [0,1536) convert W, blocks [1536,9736) convert x.
// x [B,T,D] fp32 -> xpad [B,T+1,D] f16 with zero row at t'=0.
// W[g][w][kin][n] fp32 -> Wt[g][n][w*256+kin] f16.
// ---------------------------------------------------------------------------
__global__ __launch_bounds__(256) void prep(
    const float* __restrict__ x, _Float16* __restrict__ xpad,
    const float* __restrict__ Wz, const float* __restrict__ Wf,
    const float* __restrict__ Wo, _Float16* __restrict__ Wt) {
    const int bx = blockIdx.x;
    if (bx < 1536) {  // convert_w: 1536*256 = 3*2*256*256 threads
        const int idx = bx * 256 + threadIdx.x;
        const int n = idx & 255;
        const int kin = (idx >> 8) & 255;
        const int w = (idx >> 16) & 1;
        const int g = idx >> 17;
        const float* W = (g == 0) ? Wz : (g == 1) ? Wf : Wo;
        const float v = W[(size_t)w * 65536 + (size_t)kin * 256 + n];
        Wt[((size_t)g * 256 + n) * 512 + w * 256 + kin] = (_Float16)v;
        return;
    }
    const int bxx = bx - 1536;        // 8200 blocks: 1025 per batch
    const int b = bxx / 1025;
    const int tb = bxx - b * 1025;
    const int tp = tb * 4 + (threadIdx.x >> 6);  // padded row 0..4096
    const int q = threadIdx.x & 63;
    if (tp > TDIM) return;
    float4 v = make_float4(0.f, 0.f, 0.f, 0.f);
    if (tp > 0)
        v = *(const float4*)(x + ((size_t)b * TDIM + tp - 1) * DDIM + q * 4);
    f16x4 h;
    h[0] = (_Float16)v.x; h[1] = (_Float16)v.y;
    h[2] = (_Float16)v.z; h[3] = (_Float16)v.w;
    *(f16x4*)(xpad + ((size_t)b * (TDIM + 1) + tp) * DDIM + q * 4) = h;
}

// ---------------------------------------------------------------------------
// MFMA GEMM, register-pipelined counted-wait loop.
// Per iteration t: vmcnt(4) [slot t+1 staged] -> barrier -> STAGE(t+3) ->
// issue ds_reads for step t+1 -> lgkmcnt(8) [step-t frags ready, step-t+1
// reads stay IN FLIGHT under the MFMAs] -> 16 MFMA on step t.
// ds_read latency hides under MFMA; staging loads have 2-iteration cover.
// Slot-overwrite safety: R(t-1) drained by iter t-1's lgkmcnt(8), which
// precedes barrier(t); STAGE(t+3) (overwrites slot (t-1)&3) issues after
// barrier(t) and its LDS writes land >=200cy later.
// XCD-aware swizzle + (n,gate)-innermost decode (A-tile L2-hot, R3-verified).
// LDS XOR chunk-swizzle (zero bank conflicts, R2-verified).
// Swapped-operand epilogue -> direct f16x4 stores (R2-verified).
// ---------------------------------------------------------------------------
__global__ __launch_bounds__(256) void gates_mfma(
    const _Float16* __restrict__ xpad, const _Float16* __restrict__ Wt,
    const float* __restrict__ bz, const float* __restrict__ bfv,
    const float* __restrict__ bo,
    _Float16* __restrict__ zbuf, _Float16* __restrict__ fbuf,
    _Float16* __restrict__ obuf) {
    // XCD swizzle: 1536 blocks = 8 XCDs x 192; hw&7 == XCD.
    const int hw = blockIdx.x;
    const int logical = (hw & 7) * 192 + (hw >> 3);
    const int mblk = logical / 6;
    const int rem = logical - mblk * 6;   // (n,gate) innermost
    const int gate = rem % 3;
    const int nblk = rem / 3;
    const int m0 = mblk * 128;
    const int n0 = nblk * 128;

    const int tid = threadIdx.x;
    const int lane = tid & 63;
    const int wave = tid >> 6;
    const int wr = wave >> 1;  // wave row (0..1)
    const int wc = wave & 1;   // wave col (0..1)

    // 4 staging slots of 16 KiB (A 8K | B 8K) = 64 KiB -> 2 blocks/CU.
    __shared__ __align__(16) char smem[65536];

    // Staging: segment s covers LDS row s>>2, chunk pos s&3; linear dest
    // position (row, cpos) holds global chunk cpos ^ ((row>>1)&3).
    const int s = wave * 64 + lane;
    const int r1 = s >> 2;
    const int kc = (((s & 3) ^ ((s >> 3) & 3))) * 8;  // swizzled src chunk

    const int b = m0 >> 12;
    const int t0 = m0 & (TDIM - 1);

    const _Float16* srcA1 =
        xpad + ((size_t)b * (TDIM + 1) + t0 + r1) * DDIM + kc;
    const _Float16* srcA2 = srcA1 + (size_t)64 * DDIM;
    const _Float16* srcB1 = Wt + ((size_t)gate * 256 + n0 + r1) * 512 + kc;
    const _Float16* srcB2 = srcB1 + (size_t)64 * 512;

#define STAGE_(slot, t)                                                      \
    {                                                                        \
        char* dA = smem + (slot) * 16384 + wave * 1024;                      \
        char* dB = smem + (slot) * 16384 + 8192 + wave * 1024;               \
        GLOAD_LDS16(srcA1 + (t) * 32, dA);                                   \
        GLOAD_LDS16(srcA2 + (t) * 32, dA + 4096);                            \
        GLOAD_LDS16(srcB1 + (t) * 32, dB);                                   \
        GLOAD_LDS16(srcB2 + (t) * 32, dB + 4096);                            \
    }

    f32x4 acc[4][4] = {};
    f16x8 aR[2][4], bR[2][4];  // register double-buffer ([t&1]: static idx)
    const int am = lane & 15;
    // Read-side swizzle: chunk c = lane>>4, cpos = c ^ ((am>>1)&3).
    const int kswz = (((lane >> 4) ^ ((lane >> 1) & 3))) * 8;  // halves

#define READ_FRAGS(buf, slot)                                                \
    {                                                                        \
        const _Float16* Ab = (const _Float16*)(smem + (slot) * 16384);       \
        const _Float16* Bb =                                                 \
            (const _Float16*)(smem + (slot) * 16384 + 8192);                 \
        _Pragma("unroll") for (int i = 0; i < 4; ++i) aR[buf][i] =           \
            *(const f16x8*)(Ab + (wr * 64 + i * 16 + am) * 32 + kswz);       \
        _Pragma("unroll") for (int j = 0; j < 4; ++j) bR[buf][j] =           \
            *(const f16x8*)(Bb + (wc * 64 + j * 16 + am) * 32 + kswz);       \
    }

    // Prologue: stage K-steps 0..2 (12 loads); slot0 ready; issue R(0).
    STAGE_(0, 0);
    STAGE_(1, 1);
    STAGE_(2, 2);
    asm volatile("s_waitcnt vmcnt(8)" ::: "memory");  // own slot-0 loads done
    __builtin_amdgcn_s_barrier();                     // all waves: slot0 ready
    __builtin_amdgcn_sched_barrier(0);
    READ_FRAGS(0, 0);

#pragma unroll
    for (int t = 0; t < 16; ++t) {
        const int cur = t & 1;
        if (t < 15) {
            // Slot t+1 staged?  In flight before wait: stages {t+1, t+2}.
            if (t <= 13)
                asm volatile("s_waitcnt vmcnt(4)" ::: "memory");
            else
                asm volatile("s_waitcnt vmcnt(0)" ::: "memory");
            __builtin_amdgcn_s_barrier();
            __builtin_amdgcn_sched_barrier(0);
            if (t < 13) STAGE_((t + 3) & 3, t + 3);
            READ_FRAGS(cur ^ 1, (t + 1) & 3);
            // Drain R(t) (issued last iter); leave R(t+1)'s 8 in flight.
            asm volatile("s_waitcnt lgkmcnt(8)" ::: "memory");
        } else {
            asm volatile("s_waitcnt lgkmcnt(0)" ::: "memory");
        }
        __builtin_amdgcn_sched_barrier(0);  // rule 18: no MFMA hoist over wait
        __builtin_amdgcn_s_setprio(1);
        // SWAPPED operands: per lane, acc[i][j] reg r = C[m][n] with
        // m = i*16 + (lane&15), n = j*16 + (lane>>4)*4 + r.
#pragma unroll
        for (int i = 0; i < 4; ++i)
#pragma unroll
            for (int j = 0; j < 4; ++j)
                acc[i][j] = __builtin_amdgcn_mfma_f32_16x16x32_f16(
                    bR[cur][j], aR[cur][i], acc[i][j], 0, 0, 0);
        __builtin_amdgcn_s_setprio(0);
    }
#undef STAGE_
#undef READ_FRAGS

    // Epilogue: per (i,j) frag = 4 consecutive columns at one row.
    // float4 bias load, activation, one 8-B f16x4 store. No LDS, no barrier.
    const float* bias = (gate == 0) ? bz : (gate == 1) ? bfv : bo;
    _Float16* outp = (gate == 0) ? zbuf : (gate == 1) ? fbuf : obuf;
    const int nq = (lane >> 4) * 4;  // n within 16-frag (4 consecutive)
#pragma unroll
    for (int i = 0; i < 4; ++i) {
        const size_t gm = (size_t)(m0 + wr * 64 + i * 16 + am);
#pragma unroll
        for (int j = 0; j < 4; ++j) {
            const int gc = n0 + wc * 64 + j * 16 + nq;
            const float4 b4 = *(const float4*)(bias + gc);
            f32x4 v = acc[i][j];
            f16x4 h;
            if (gate == 0) {
                h[0] = (_Float16)tanh_(v[0] + b4.x);
                h[1] = (_Float16)tanh_(v[1] + b4.y);
                h[2] = (_Float16)tanh_(v[2] + b4.z);
                h[3] = (_Float16)tanh_(v[3] + b4.w);
            } else {
                h[0] = (_Float16)sigmoid_(v[0] + b4.x);
                h[1] = (_Float16)sigmoid_(v[1] + b4.y);
                h[2] = (_Float16)sigmoid_(v[2] + b4.z);
                h[3] = (_Float16)sigmoid_(v[3] + b4.w);
            }
            *(f16x4*)(outp + gm * DDIM + gc) = h;
        }
    }
}

// ---------------------------------------------------------------------------
// Scan pass 1: per-chunk aggregates over LCHUNK steps from c=0; A = prod(f).
// 4 channels/thread -> 131072 threads (2 waves/SIMD) for latency hiding.
// ---------------------------------------------------------------------------
__global__ __launch_bounds__(256) void scan_pass1(
    const _Float16* __restrict__ zbuf, const _Float16* __restrict__ fbuf,
    float* __restrict__ aggA, float* __restrict__ aggB) {
    const int idx = blockIdx.x * 256 + threadIdx.x;  // < B*NCHUNK*64 = 131072
    const int d4 = idx & 63;
    const int chunk = (idx >> 6) & (NCHUNK - 1);
    const int b = idx >> 14;

    const size_t row0 = (size_t)b * TDIM + (size_t)chunk * LCHUNK;
    const int2* zp = (const int2*)zbuf + row0 * 64 + d4;
    const int2* fp = (const int2*)fbuf + row0 * 64 + d4;

    float A[4], c[4];
#pragma unroll
    for (int e = 0; e < 4; ++e) { A[e] = 1.0f; c[e] = 0.0f; }

    for (int i = 0; i < LCHUNK; ++i) {
        int2 fv = *fp;
        int2 zv = *zp;
        const _Float16* fh = (const _Float16*)&fv;
        const _Float16* zh = (const _Float16*)&zv;
#pragma unroll
        for (int e = 0; e < 4; ++e) {
            const float f = (float)fh[e];
            const float z = (float)zh[e];
            A[e] *= f;
            c[e] = f * c[e] + (1.0f - f) * z;
        }
        fp += 64;
        zp += 64;
    }
    ((float4*)aggA)[idx] = make_float4(A[0], A[1], A[2], A[3]);
    ((float4*)aggB)[idx] = make_float4(c[0], c[1], c[2], c[3]);
}

// ---------------------------------------------------------------------------
// Carry scan across chunks: one thread per (b,d) = 2048 threads.
// Unroll-16 batched loads: 16 latency rounds instead of 32.
// ---------------------------------------------------------------------------
__global__ __launch_bounds__(256) void carry_scan(
    const float* __restrict__ aggA, const float* __restrict__ aggB,
    float* __restrict__ carry) {
    const int g = blockIdx.x * 256 + threadIdx.x;  // < B*D = 2048
    const int d = g & 255;
    const int b = g >> 8;
    const size_t base = (size_t)b * NCHUNK * 256 + d;

    float c = 0.0f;
    for (int ch0 = 0; ch0 < NCHUNK; ch0 += 16) {
        float A[16], Bv[16];
#pragma unroll
        for (int u = 0; u < 16; ++u) {
            const size_t p = base + (size_t)(ch0 + u) * 256;
            A[u] = aggA[p];
            Bv[u] = aggB[p];
        }
#pragma unroll
        for (int u = 0; u < 16; ++u) {
            const size_t p = base + (size_t)(ch0 + u) * 256;
            carry[p] = c;
            c = A[u] * c + Bv[u];
        }
    }
}

// ---------------------------------------------------------------------------
// Scan pass 2: replay chunk with true carry; h = o*c -> fp32 out.
// 4 channels/thread -> 131072 threads; one float4 store per step.
// ---------------------------------------------------------------------------
__global__ __launch_bounds__(256) void scan_pass2(
    const _Float16* __restrict__ zbuf, const _Float16* __restrict__ fbuf,
    const _Float16* __restrict__ obuf, const float* __restrict__ carry,
    float* __restrict__ out) {
    const int idx = blockIdx.x * 256 + threadIdx.x;  // < 131072
    const int d4 = idx & 63;
    const int chunk = (idx >> 6) & (NCHUNK - 1);
    const int b = idx >> 14;

    float c[4];
    const float4 c0 = ((const float4*)carry)[idx];
    c[0] = c0.x; c[1] = c0.y; c[2] = c0.z; c[3] = c0.w;

    const size_t row0 = (size_t)b * TDIM + (size_t)chunk * LCHUNK;
    const int2* zp = (const int2*)zbuf + row0 * 64 + d4;
    const int2* fp = (const int2*)fbuf + row0 * 64 + d4;
    const int2* op = (const int2*)obuf + row0 * 64 + d4;
    float4* hp = (float4*)out + row0 * 64 + d4;

    for (int i = 0; i < LCHUNK; ++i) {
        int2 fv = *fp;
        int2 zv = *zp;
        int2 ov = *op;
        const _Float16* fh = (const _Float16*)&fv;
        const _Float16* zh = (const _Float16*)&zv;
        const _Float16* oh = (const _Float16*)&ov;
        float h[4];
#pragma unroll
        for (int e = 0; e < 4; ++e) {
            const float f = (float)fh[e];
            const float z = (float)zh[e];
            c[e] = f * c[e] + (1.0f - f) * z;
            h[e] = (float)oh[e] * c[e];
        }
        *hp = make_float4(h[0], h[1], h[2], h[3]);
        fp += 64;
        zp += 64;
        op += 64;
        hp += 64;
    }
}

extern "C" void kernel_launch(void* const* d_in, const int* in_sizes, int n_in,
                              void* d_out, int out_size, void* d_ws,
                              size_t ws_size, hipStream_t stream) {
    const float* x = (const float*)d_in[0];
    const float* Wz = (const float*)d_in[1];
    const float* Wf = (const float*)d_in[2];
    const float* Wo = (const float*)d_in[3];
    const float* bz = (const float*)d_in[4];
    const float* bfv = (const float*)d_in[5];
    const float* bo = (const float*)d_in[6];
    float* out = (float*)d_out;

    // Workspace (bytes): xpad 16.78M | Wt 0.79M | z 16.78M | f 16.78M |
    // o 16.78M | aggA 2M | aggB 2M | carry 2M   -> ~74.7 MB
    char* p = (char*)d_ws;
    _Float16* xpad = (_Float16*)p;  p += (size_t)BDIM * (TDIM + 1) * DDIM * 2;
    _Float16* Wt = (_Float16*)p;    p += (size_t)3 * 256 * 512 * 2;
    _Float16* zbuf = (_Float16*)p;  p += (size_t)MDIM * DDIM * 2;
    _Float16* fbuf = (_Float16*)p;  p += (size_t)MDIM * DDIM * 2;
    _Float16* obuf = (_Float16*)p;  p += (size_t)MDIM * DDIM * 2;
    float* aggA = (float*)p;        p += (size_t)BDIM * NCHUNK * DDIM * 4;
    float* aggB = (float*)p;        p += (size_t)BDIM * NCHUNK * DDIM * 4;
    float* carry = (float*)p;

    prep<<<1536 + 1025 * BDIM, 256, 0, stream>>>(x, xpad, Wz, Wf, Wo, Wt);

    gates_mfma<<<MDIM / 128 * (DDIM / 128) * 3, 256, 0, stream>>>(
        xpad, Wt, bz, bfv, bo, zbuf, fbuf, obuf);

    scan_pass1<<<(BDIM * NCHUNK * 64) / 256, 256, 0, stream>>>(zbuf, fbuf,
                                                               aggA, aggB);
    carry_scan<<<(BDIM * DDIM) / 256, 256, 0, stream>>>(aggA, aggB, carry);
    scan_pass2<<<(BDIM * NCHUNK * 64) / 256, 256, 0, stream>>>(zbuf, fbuf,
                                                               obuf, carry, out);
}

// Round 6
// 162.686 us; speedup vs baseline: 1.0838x; 1.0133x over previous
//
#include <hip/hip_runtime.h>
#include <hip/hip_bf16.h>
#include <hip/hip_fp16.h>

// Problem constants (B=8, T=4096, Din=Dout=256, WINDOW=2)
#define BDIM 8
#define TDIM 4096
#define DDIM 256
#define MDIM (BDIM * TDIM)      // 32768
#define NCHUNK 256              // chunks along T for the parallel scan
#define LCHUNK (TDIM / NCHUNK)  // 16

typedef _Float16 f16x8 __attribute__((ext_vector_type(8)));
typedef _Float16 f16x4 __attribute__((ext_vector_type(4)));
typedef float f32x4 __attribute__((ext_vector_type(4)));

__device__ __forceinline__ float sigmoid_(float x) {
    return 1.0f / (1.0f + __expf(-x));
}
__device__ __forceinline__ float tanh_(float x) {
    return 2.0f / (1.0f + __expf(-2.0f * x)) - 1.0f;
}

#define GLOAD_LDS16(g, l)                                                    \
    __builtin_amdgcn_global_load_lds(                                        \
        (const __attribute__((address_space(1))) void*)(g),                  \
        (__attribute__((address_space(3))) void*)(l), 16, 0, 0)

// ---------------------------------------------------------------------------
// Fused prep: blocks [0,1536) convert W, blocks [1536,9736) convert x.
// x [B,T,D] fp32 -> xpad [B,T+1,D] f16 with zero row at t'=0.
// W[g][w][kin][n] fp32 -> Wt[g][n][w*256+kin] f16.
// ---------------------------------------------------------------------------
__global__ __launch_bounds__(256) void prep(
    const float* __restrict__ x, _Float16* __restrict__ xpad,
    const float* __restrict__ Wz, const float* __restrict__ Wf,
    const float* __restrict__ Wo, _Float16* __restrict__ Wt) {
    const int bx = blockIdx.x;
    if (bx < 1536) {  // convert_w: 1536*256 = 3*2*256*256 threads
        const int idx = bx * 256 + threadIdx.x;
        const int n = idx & 255;
        const int kin = (idx >> 8) & 255;
        const int w = (idx >> 16) & 1;
        const int g = idx >> 17;
        const float* W = (g == 0) ? Wz : (g == 1) ? Wf : Wo;
        const float v = W[(size_t)w * 65536 + (size_t)kin * 256 + n];
        Wt[((size_t)g * 256 + n) * 512 + w * 256 + kin] = (_Float16)v;
        return;
    }
    const int bxx = bx - 1536;        // 8200 blocks: 1025 per batch
    const int b = bxx / 1025;
    const int tb = bxx - b * 1025;
    const int tp = tb * 4 + (threadIdx.x >> 6);  // padded row 0..4096
    const int q = threadIdx.x & 63;
    if (tp > TDIM) return;
    float4 v = make_float4(0.f, 0.f, 0.f, 0.f);
    if (tp > 0)
        v = *(const float4*)(x + ((size_t)b * TDIM + tp - 1) * DDIM + q * 4);
    f16x4 h;
    h[0] = (_Float16)v.x; h[1] = (_Float16)v.y;
    h[2] = (_Float16)v.z; h[3] = (_Float16)v.w;
    *(f16x4*)(xpad + ((size_t)b * (TDIM + 1) + tp) * DDIM + q * 4) = h;
}

// ---------------------------------------------------------------------------
// MFMA GEMM.  2 LDS slots (32 KB) -> 4 blocks/CU -> 4 waves/SIMD.
// Four rounds showed the schedule was never the limit: at 2 waves/SIMD the
// matrix pipe idles whenever both waves wait.  TLP across 4 independent
// (un-synced) blocks per CU fills the stalls (m114 mechanism).
// Ring safety: slot (t+1)&1's prior readers drained (lgkmcnt(0)) before
// their iter t-1 MFMAs, hence before this barrier; STAGE(t+1) after it.
// Own vmcnt(0) + barrier ==> slot t&1 staged by all waves.
// XCD-aware swizzle + (n,gate)-innermost decode (FETCH 41->11.5 MB, R3).
// LDS XOR chunk-swizzle (zero bank conflicts, R2).
// Swapped-operand epilogue -> direct f16x4 stores (R2).
// ---------------------------------------------------------------------------
__global__ __launch_bounds__(256, 4) void gates_mfma(
    const _Float16* __restrict__ xpad, const _Float16* __restrict__ Wt,
    const float* __restrict__ bz, const float* __restrict__ bfv,
    const float* __restrict__ bo,
    _Float16* __restrict__ zbuf, _Float16* __restrict__ fbuf,
    _Float16* __restrict__ obuf) {
    // XCD swizzle: 1536 blocks = 8 XCDs x 192; hw&7 == XCD.
    const int hw = blockIdx.x;
    const int logical = (hw & 7) * 192 + (hw >> 3);
    const int mblk = logical / 6;
    const int rem = logical - mblk * 6;   // (n,gate) innermost
    const int gate = rem % 3;
    const int nblk = rem / 3;
    const int m0 = mblk * 128;
    const int n0 = nblk * 128;

    const int tid = threadIdx.x;
    const int lane = tid & 63;
    const int wave = tid >> 6;
    const int wr = wave >> 1;  // wave row (0..1)
    const int wc = wave & 1;   // wave col (0..1)

    // 2 staging slots of 16 KiB (A 8K | B 8K) = 32 KiB -> 4 blocks/CU.
    __shared__ __align__(16) char smem[32768];

    // Staging: segment s covers LDS row s>>2, chunk pos s&3; linear dest
    // position (row, cpos) holds global chunk cpos ^ ((row>>1)&3).
    const int s = wave * 64 + lane;
    const int r1 = s >> 2;
    const int kc = (((s & 3) ^ ((s >> 3) & 3))) * 8;  // swizzled src chunk

    const int b = m0 >> 12;
    const int t0 = m0 & (TDIM - 1);

    const _Float16* srcA1 =
        xpad + ((size_t)b * (TDIM + 1) + t0 + r1) * DDIM + kc;
    const _Float16* srcA2 = srcA1 + (size_t)64 * DDIM;
    const _Float16* srcB1 = Wt + ((size_t)gate * 256 + n0 + r1) * 512 + kc;
    const _Float16* srcB2 = srcB1 + (size_t)64 * 512;

#define STAGE_(slot, t)                                                      \
    {                                                                        \
        char* dA = smem + (slot) * 16384 + wave * 1024;                      \
        char* dB = smem + (slot) * 16384 + 8192 + wave * 1024;               \
        GLOAD_LDS16(srcA1 + (t) * 32, dA);                                   \
        GLOAD_LDS16(srcA2 + (t) * 32, dA + 4096);                            \
        GLOAD_LDS16(srcB1 + (t) * 32, dB);                                   \
        GLOAD_LDS16(srcB2 + (t) * 32, dB + 4096);                            \
    }

    f32x4 acc[4][4] = {};
    const int am = lane & 15;
    // Read-side swizzle: chunk c = lane>>4, cpos = c ^ ((am>>1)&3).
    const int kswz = (((lane >> 4) ^ ((lane >> 1) & 3))) * 8;  // halves

    // Prologue: stage K-step 0 into slot 0.
    STAGE_(0, 0);

#pragma unroll
    for (int t = 0; t < 16; ++t) {
        // Own stage(t) loads done (they had all of iter t-1 as cover), then
        // barrier: slot t&1 fully staged by all waves.
        asm volatile("s_waitcnt vmcnt(0)" ::: "memory");
        __builtin_amdgcn_s_barrier();
        __builtin_amdgcn_sched_barrier(0);
        // Slot (t+1)&1 was read in iter t-1; those ds_reads drained before
        // that iter's MFMAs (lgkmcnt(0)), hence before the barrier above.
        if (t < 15) STAGE_((t + 1) & 1, t + 1);

        const _Float16* Ab = (const _Float16*)(smem + (t & 1) * 16384);
        const _Float16* Bb = (const _Float16*)(smem + (t & 1) * 16384 + 8192);

        f16x8 a[4], bb[4];
#pragma unroll
        for (int i = 0; i < 4; ++i)
            a[i] = *(const f16x8*)(Ab + (wr * 64 + i * 16 + am) * 32 + kswz);
#pragma unroll
        for (int j = 0; j < 4; ++j)
            bb[j] = *(const f16x8*)(Bb + (wc * 64 + j * 16 + am) * 32 + kswz);

        asm volatile("s_waitcnt lgkmcnt(0)" ::: "memory");
        __builtin_amdgcn_sched_barrier(0);  // rule 18: no MFMA hoist over wait
        __builtin_amdgcn_s_setprio(1);
        // SWAPPED operands: per lane, acc[i][j] reg r = C[m][n] with
        // m = i*16 + (lane&15), n = j*16 + (lane>>4)*4 + r.
#pragma unroll
        for (int i = 0; i < 4; ++i)
#pragma unroll
            for (int j = 0; j < 4; ++j)
                acc[i][j] = __builtin_amdgcn_mfma_f32_16x16x32_f16(
                    bb[j], a[i], acc[i][j], 0, 0, 0);
        __builtin_amdgcn_s_setprio(0);
    }
#undef STAGE_

    // Epilogue: per (i,j) frag = 4 consecutive columns at one row.
    // float4 bias load, activation, one 8-B f16x4 store. No LDS, no barrier.
    const float* bias = (gate == 0) ? bz : (gate == 1) ? bfv : bo;
    _Float16* outp = (gate == 0) ? zbuf : (gate == 1) ? fbuf : obuf;
    const int nq = (lane >> 4) * 4;  // n within 16-frag (4 consecutive)
#pragma unroll
    for (int i = 0; i < 4; ++i) {
        const size_t gm = (size_t)(m0 + wr * 64 + i * 16 + am);
#pragma unroll
        for (int j = 0; j < 4; ++j) {
            const int gc = n0 + wc * 64 + j * 16 + nq;
            const float4 b4 = *(const float4*)(bias + gc);
            f32x4 v = acc[i][j];
            f16x4 h;
            if (gate == 0) {
                h[0] = (_Float16)tanh_(v[0] + b4.x);
                h[1] = (_Float16)tanh_(v[1] + b4.y);
                h[2] = (_Float16)tanh_(v[2] + b4.z);
                h[3] = (_Float16)tanh_(v[3] + b4.w);
            } else {
                h[0] = (_Float16)sigmoid_(v[0] + b4.x);
                h[1] = (_Float16)sigmoid_(v[1] + b4.y);
                h[2] = (_Float16)sigmoid_(v[2] + b4.z);
                h[3] = (_Float16)sigmoid_(v[3] + b4.w);
            }
            *(f16x4*)(outp + gm * DDIM + gc) = h;
        }
    }
}

// ---------------------------------------------------------------------------
// Scan pass 1: per-chunk aggregates over LCHUNK steps from c=0; A = prod(f).
// 4 channels/thread -> 131072 threads (2 waves/SIMD) for latency hiding.
// ---------------------------------------------------------------------------
__global__ __launch_bounds__(256) void scan_pass1(
    const _Float16* __restrict__ zbuf, const _Float16* __restrict__ fbuf,
    float* __restrict__ aggA, float* __restrict__ aggB) {
    const int idx = blockIdx.x * 256 + threadIdx.x;  // < B*NCHUNK*64 = 131072
    const int d4 = idx & 63;
    const int chunk = (idx >> 6) & (NCHUNK - 1);
    const int b = idx >> 14;

    const size_t row0 = (size_t)b * TDIM + (size_t)chunk * LCHUNK;
    const int2* zp = (const int2*)zbuf + row0 * 64 + d4;
    const int2* fp = (const int2*)fbuf + row0 * 64 + d4;

    float A[4], c[4];
#pragma unroll
    for (int e = 0; e < 4; ++e) { A[e] = 1.0f; c[e] = 0.0f; }

    for (int i = 0; i < LCHUNK; ++i) {
        int2 fv = *fp;
        int2 zv = *zp;
        const _Float16* fh = (const _Float16*)&fv;
        const _Float16* zh = (const _Float16*)&zv;
#pragma unroll
        for (int e = 0; e < 4; ++e) {
            const float f = (float)fh[e];
            const float z = (float)zh[e];
            A[e] *= f;
            c[e] = f * c[e] + (1.0f - f) * z;
        }
        fp += 64;
        zp += 64;
    }
    ((float4*)aggA)[idx] = make_float4(A[0], A[1], A[2], A[3]);
    ((float4*)aggB)[idx] = make_float4(c[0], c[1], c[2], c[3]);
}

// ---------------------------------------------------------------------------
// Carry scan across chunks: one thread per (b,d) = 2048 threads.
// Unroll-16 batched loads: 16 latency rounds instead of 32.
// ---------------------------------------------------------------------------
__global__ __launch_bounds__(256) void carry_scan(
    const float* __restrict__ aggA, const float* __restrict__ aggB,
    float* __restrict__ carry) {
    const int g = blockIdx.x * 256 + threadIdx.x;  // < B*D = 2048
    const int d = g & 255;
    const int b = g >> 8;
    const size_t base = (size_t)b * NCHUNK * 256 + d;

    float c = 0.0f;
    for (int ch0 = 0; ch0 < NCHUNK; ch0 += 16) {
        float A[16], Bv[16];
#pragma unroll
        for (int u = 0; u < 16; ++u) {
            const size_t p = base + (size_t)(ch0 + u) * 256;
            A[u] = aggA[p];
            Bv[u] = aggB[p];
        }
#pragma unroll
        for (int u = 0; u < 16; ++u) {
            const size_t p = base + (size_t)(ch0 + u) * 256;
            carry[p] = c;
            c = A[u] * c + Bv[u];
        }
    }
}

// ---------------------------------------------------------------------------
// Scan pass 2: replay chunk with true carry; h = o*c -> fp32 out.
// 4 channels/thread -> 131072 threads; one float4 store per step.
// ---------------------------------------------------------------------------
__global__ __launch_bounds__(256) void scan_pass2(
    const _Float16* __restrict__ zbuf, const _Float16* __restrict__ fbuf,
    const _Float16* __restrict__ obuf, const float* __restrict__ carry,
    float* __restrict__ out) {
    const int idx = blockIdx.x * 256 + threadIdx.x;  // < 131072
    const int d4 = idx & 63;
    const int chunk = (idx >> 6) & (NCHUNK - 1);
    const int b = idx >> 14;

    float c[4];
    const float4 c0 = ((const float4*)carry)[idx];
    c[0] = c0.x; c[1] = c0.y; c[2] = c0.z; c[3] = c0.w;

    const size_t row0 = (size_t)b * TDIM + (size_t)chunk * LCHUNK;
    const int2* zp = (const int2*)zbuf + row0 * 64 + d4;
    const int2* fp = (const int2*)fbuf + row0 * 64 + d4;
    const int2* op = (const int2*)obuf + row0 * 64 + d4;
    float4* hp = (float4*)out + row0 * 64 + d4;

    for (int i = 0; i < LCHUNK; ++i) {
        int2 fv = *fp;
        int2 zv = *zp;
        int2 ov = *op;
        const _Float16* fh = (const _Float16*)&fv;
        const _Float16* zh = (const _Float16*)&zv;
        const _Float16* oh = (const _Float16*)&ov;
        float h[4];
#pragma unroll
        for (int e = 0; e < 4; ++e) {
            const float f = (float)fh[e];
            const float z = (float)zh[e];
            c[e] = f * c[e] + (1.0f - f) * z;
            h[e] = (float)oh[e] * c[e];
        }
        *hp = make_float4(h[0], h[1], h[2], h[3]);
        fp += 64;
        zp += 64;
        op += 64;
        hp += 64;
    }
}

extern "C" void kernel_launch(void* const* d_in, const int* in_sizes, int n_in,
                              void* d_out, int out_size, void* d_ws,
                              size_t ws_size, hipStream_t stream) {
    const float* x = (const float*)d_in[0];
    const float* Wz = (const float*)d_in[1];
    const float* Wf = (const float*)d_in[2];
    const float* Wo = (const float*)d_in[3];
    const float* bz = (const float*)d_in[4];
    const float* bfv = (const float*)d_in[5];
    const float* bo = (const float*)d_in[6];
    float* out = (float*)d_out;

    // Workspace (bytes): xpad 16.78M | Wt 0.79M | z 16.78M | f 16.78M |
    // o 16.78M | aggA 2M | aggB 2M | carry 2M   -> ~74.7 MB
    char* p = (char*)d_ws;
    _Float16* xpad = (_Float16*)p;  p += (size_t)BDIM * (TDIM + 1) * DDIM * 2;
    _Float16* Wt = (_Float16*)p;    p += (size_t)3 * 256 * 512 * 2;
    _Float16* zbuf = (_Float16*)p;  p += (size_t)MDIM * DDIM * 2;
    _Float16* fbuf = (_Float16*)p;  p += (size_t)MDIM * DDIM * 2;
    _Float16* obuf = (_Float16*)p;  p += (size_t)MDIM * DDIM * 2;
    float* aggA = (float*)p;        p += (size_t)BDIM * NCHUNK * DDIM * 4;
    float* aggB = (float*)p;        p += (size_t)BDIM * NCHUNK * DDIM * 4;
    float* carry = (float*)p;

    prep<<<1536 + 1025 * BDIM, 256, 0, stream>>>(x, xpad, Wz, Wf, Wo, Wt);

    gates_mfma<<<MDIM / 128 * (DDIM / 128) * 3, 256, 0, stream>>>(
        xpad, Wt, bz, bfv, bo, zbuf, fbuf, obuf);

    scan_pass1<<<(BDIM * NCHUNK * 64) / 256, 256, 0, stream>>>(zbuf, fbuf,
                                                               aggA, aggB);
    carry_scan<<<(BDIM * DDIM) / 256, 256, 0, stream>>>(aggA, aggB, carry);
    scan_pass2<<<(BDIM * NCHUNK * 64) / 256, 256, 0, stream>>>(zbuf, fbuf,
                                                               obuf, carry, out);
}

// Round 7
// 159.276 us; speedup vs baseline: 1.1070x; 1.0214x over previous
//
#include <hip/hip_runtime.h>
#include <hip/hip_bf16.h>
#include <hip/hip_fp16.h>

// Problem constants (B=8, T=4096, Din=Dout=256, WINDOW=2)
#define BDIM 8
#define TDIM 4096
#define DDIM 256
#define MDIM (BDIM * TDIM)      // 32768
#define NCHUNK 256              // chunks along T for the parallel scan
#define LCHUNK (TDIM / NCHUNK)  // 16

typedef _Float16 f16x8 __attribute__((ext_vector_type(8)));
typedef _Float16 f16x4 __attribute__((ext_vector_type(4)));
typedef float f32x4 __attribute__((ext_vector_type(4)));

__device__ __forceinline__ float sigmoid_(float x) {
    return 1.0f / (1.0f + __expf(-x));
}
__device__ __forceinline__ float tanh_(float x) {
    return 2.0f / (1.0f + __expf(-2.0f * x)) - 1.0f;
}

#define GLOAD_LDS16(g, l)                                                    \
    __builtin_amdgcn_global_load_lds(                                        \
        (const __attribute__((address_space(1))) void*)(g),                  \
        (__attribute__((address_space(3))) void*)(l), 16, 0, 0)

// ---------------------------------------------------------------------------
// Fused prep: blocks [0,1536) convert W, blocks [1536,9736) convert x.
// x [B,T,D] fp32 -> xpad [B,T+1,D] f16 with zero row at t'=0.
// W[g][w][kin][n] fp32 -> Wt[g][n][w*256+kin] f16.
// ---------------------------------------------------------------------------
__global__ __launch_bounds__(256) void prep(
    const float* __restrict__ x, _Float16* __restrict__ xpad,
    const float* __restrict__ Wz, const float* __restrict__ Wf,
    const float* __restrict__ Wo, _Float16* __restrict__ Wt) {
    const int bx = blockIdx.x;
    if (bx < 1536) {  // convert_w: 1536*256 = 3*2*256*256 threads
        const int idx = bx * 256 + threadIdx.x;
        const int n = idx & 255;
        const int kin = (idx >> 8) & 255;
        const int w = (idx >> 16) & 1;
        const int g = idx >> 17;
        const float* W = (g == 0) ? Wz : (g == 1) ? Wf : Wo;
        const float v = W[(size_t)w * 65536 + (size_t)kin * 256 + n];
        Wt[((size_t)g * 256 + n) * 512 + w * 256 + kin] = (_Float16)v;
        return;
    }
    const int bxx = bx - 1536;        // 8200 blocks: 1025 per batch
    const int b = bxx / 1025;
    const int tb = bxx - b * 1025;
    const int tp = tb * 4 + (threadIdx.x >> 6);  // padded row 0..4096
    const int q = threadIdx.x & 63;
    if (tp > TDIM) return;
    float4 v = make_float4(0.f, 0.f, 0.f, 0.f);
    if (tp > 0)
        v = *(const float4*)(x + ((size_t)b * TDIM + tp - 1) * DDIM + q * 4);
    f16x4 h;
    h[0] = (_Float16)v.x; h[1] = (_Float16)v.y;
    h[2] = (_Float16)v.z; h[3] = (_Float16)v.w;
    *(f16x4*)(xpad + ((size_t)b * (TDIM + 1) + tp) * DDIM + q * 4) = h;
}

// ---------------------------------------------------------------------------
// MFMA GEMM, BK=64 two-phase K-tiles (R6 post-mortem: work-per-barrier was
// the pinned constraint -- 16 MFMA per barrier-pair = ~25% duty cycle no
// matter the schedule or occupancy).  Now per iteration (8 total):
//   vmcnt(0)+barrier -> STAGE(next tile, 8 loads) -> issue ALL 16 ds_reads
//   (kk0 then kk1) -> lgkmcnt(8): kk0 ready, kk1 in flight -> 16 MFMA(kk0)
//   -> lgkmcnt(0) -> 16 MFMA(kk1).
// 32 MFMA (~620 cyc) per barrier, ds_read latency hidden under MFMA(kk0).
// LDS: 2 slots x (A 16K | B 16K) = 64 KB -> 2 blocks/CU.
// Swizzle for 128-B rows (every row spans all 32 banks): linear-dest
// position (row, cpos) holds global chunk cpos ^ (row&7); read applies the
// same XOR (row&7 == lane&7 for all frags) -> max 2-way aliasing (free).
// XCD-aware swizzle + (n,gate)-innermost decode (FETCH 41->11.5 MB, R3).
// Swapped-operand epilogue -> direct f16x4 stores (R2).
// ---------------------------------------------------------------------------
__global__ __launch_bounds__(256, 2) void gates_mfma(
    const _Float16* __restrict__ xpad, const _Float16* __restrict__ Wt,
    const float* __restrict__ bz, const float* __restrict__ bfv,
    const float* __restrict__ bo,
    _Float16* __restrict__ zbuf, _Float16* __restrict__ fbuf,
    _Float16* __restrict__ obuf) {
    // XCD swizzle: 1536 blocks = 8 XCDs x 192; hw&7 == XCD.
    const int hw = blockIdx.x;
    const int logical = (hw & 7) * 192 + (hw >> 3);
    const int mblk = logical / 6;
    const int rem = logical - mblk * 6;   // (n,gate) innermost
    const int gate = rem % 3;
    const int nblk = rem / 3;
    const int m0 = mblk * 128;
    const int n0 = nblk * 128;

    const int tid = threadIdx.x;
    const int lane = tid & 63;
    const int wave = tid >> 6;
    const int wr = wave >> 1;  // wave row (0..1)
    const int wc = wave & 1;   // wave col (0..1)

    // 2 slots of 32 KiB: A [128][64]h at +0, B [128][64]h at +16384.
    __shared__ __align__(16) char smem[65536];

    // Staging: thread s covers row r1 = s>>3 (+32/round), chunk pos s&7.
    // Linear dest (row, cpos) must hold global chunk cpos ^ (row&7);
    // row&7 == (s>>3)&7 for every round (round step 32 == 0 mod 8).
    const int s = wave * 64 + lane;
    const int r1 = s >> 3;                              // 0..31
    const int kc = (((s & 7) ^ ((s >> 3) & 7))) * 8;    // halves, 0..56

    const int b = m0 >> 12;
    const int t0 = m0 & (TDIM - 1);

    const _Float16* srcA =
        xpad + ((size_t)b * (TDIM + 1) + t0 + r1) * DDIM + kc;
    const _Float16* srcB = Wt + ((size_t)gate * 256 + n0 + r1) * 512 + kc;

    // 8 loads per thread per K-tile: 4 A-rounds + 4 B-rounds of 32 rows.
#define STAGE_(slot, kt)                                                     \
    {                                                                        \
        char* dA = smem + (slot) * 32768 + wave * 1024;                      \
        char* dB = smem + (slot) * 32768 + 16384 + wave * 1024;              \
        GLOAD_LDS16(srcA + (kt) * 64, dA);                                   \
        GLOAD_LDS16(srcA + (kt) * 64 + 32 * DDIM, dA + 4096);                \
        GLOAD_LDS16(srcA + (kt) * 64 + 64 * DDIM, dA + 8192);                \
        GLOAD_LDS16(srcA + (kt) * 64 + 96 * DDIM, dA + 12288);               \
        GLOAD_LDS16(srcB + (kt) * 64, dB);                                   \
        GLOAD_LDS16(srcB + (kt) * 64 + 32 * 512, dB + 4096);                 \
        GLOAD_LDS16(srcB + (kt) * 64 + 64 * 512, dB + 8192);                 \
        GLOAD_LDS16(srcB + (kt) * 64 + 96 * 512, dB + 12288);                \
    }

    f32x4 acc[4][4] = {};
    const int am = lane & 15;
    // Read-side chunk (halves offset) for kk=0/1: chunk = (kk*4 + lane>>4)
    // ^ (lane&7); row&7 == lane&7 for every frag row.
    const int c0 = (((lane >> 4) ^ (lane & 7))) * 8;
    const int c1 = (((4 + (lane >> 4)) ^ (lane & 7))) * 8;

    // Prologue: stage K-tile 0 into slot 0.
    STAGE_(0, 0);

#pragma unroll
    for (int t = 0; t < 8; ++t) {
        // Own stage(t) loads done (full prior iteration of cover), then
        // barrier: slot t&1 fully staged by all waves.
        asm volatile("s_waitcnt vmcnt(0)" ::: "memory");
        __builtin_amdgcn_s_barrier();
        __builtin_amdgcn_sched_barrier(0);
        // Slot (t+1)&1's prior readers drained (lgkmcnt(0)) before their
        // iter t-1 kk1 MFMAs, hence before the barrier above.
        if (t < 7) STAGE_((t + 1) & 1, t + 1);

        const _Float16* Ab = (const _Float16*)(smem + (t & 1) * 32768);
        const _Float16* Bb = Ab + 8192;  // halves

        f16x8 a0[4], b0[4], a1[4], b1[4];
#pragma unroll
        for (int i = 0; i < 4; ++i)
            a0[i] = *(const f16x8*)(Ab + (wr * 64 + i * 16 + am) * 64 + c0);
#pragma unroll
        for (int j = 0; j < 4; ++j)
            b0[j] = *(const f16x8*)(Bb + (wc * 64 + j * 16 + am) * 64 + c0);
        __builtin_amdgcn_sched_barrier(0);  // kk0 reads issue before kk1
#pragma unroll
        for (int i = 0; i < 4; ++i)
            a1[i] = *(const f16x8*)(Ab + (wr * 64 + i * 16 + am) * 64 + c1);
#pragma unroll
        for (int j = 0; j < 4; ++j)
            b1[j] = *(const f16x8*)(Bb + (wc * 64 + j * 16 + am) * 64 + c1);

        // kk0's 8 reads done; kk1's 8 stay in flight under the MFMAs.
        asm volatile("s_waitcnt lgkmcnt(8)" ::: "memory");
        __builtin_amdgcn_sched_barrier(0);  // rule 18: no MFMA hoist
        __builtin_amdgcn_s_setprio(1);
        // SWAPPED operands: per lane, acc[i][j] reg r = C[m][n] with
        // m = i*16 + (lane&15), n = j*16 + (lane>>4)*4 + r.
#pragma unroll
        for (int i = 0; i < 4; ++i)
#pragma unroll
            for (int j = 0; j < 4; ++j)
                acc[i][j] = __builtin_amdgcn_mfma_f32_16x16x32_f16(
                    b0[j], a0[i], acc[i][j], 0, 0, 0);
        __builtin_amdgcn_s_setprio(0);
        asm volatile("s_waitcnt lgkmcnt(0)" ::: "memory");
        __builtin_amdgcn_sched_barrier(0);
        __builtin_amdgcn_s_setprio(1);
#pragma unroll
        for (int i = 0; i < 4; ++i)
#pragma unroll
            for (int j = 0; j < 4; ++j)
                acc[i][j] = __builtin_amdgcn_mfma_f32_16x16x32_f16(
                    b1[j], a1[i], acc[i][j], 0, 0, 0);
        __builtin_amdgcn_s_setprio(0);
    }
#undef STAGE_

    // Epilogue: per (i,j) frag = 4 consecutive columns at one row.
    // float4 bias load, activation, one 8-B f16x4 store. No LDS, no barrier.
    const float* bias = (gate == 0) ? bz : (gate == 1) ? bfv : bo;
    _Float16* outp = (gate == 0) ? zbuf : (gate == 1) ? fbuf : obuf;
    const int nq = (lane >> 4) * 4;  // n within 16-frag (4 consecutive)
#pragma unroll
    for (int i = 0; i < 4; ++i) {
        const size_t gm = (size_t)(m0 + wr * 64 + i * 16 + am);
#pragma unroll
        for (int j = 0; j < 4; ++j) {
            const int gc = n0 + wc * 64 + j * 16 + nq;
            const float4 b4 = *(const float4*)(bias + gc);
            f32x4 v = acc[i][j];
            f16x4 h;
            if (gate == 0) {
                h[0] = (_Float16)tanh_(v[0] + b4.x);
                h[1] = (_Float16)tanh_(v[1] + b4.y);
                h[2] = (_Float16)tanh_(v[2] + b4.z);
                h[3] = (_Float16)tanh_(v[3] + b4.w);
            } else {
                h[0] = (_Float16)sigmoid_(v[0] + b4.x);
                h[1] = (_Float16)sigmoid_(v[1] + b4.y);
                h[2] = (_Float16)sigmoid_(v[2] + b4.z);
                h[3] = (_Float16)sigmoid_(v[3] + b4.w);
            }
            *(f16x4*)(outp + gm * DDIM + gc) = h;
        }
    }
}

// ---------------------------------------------------------------------------
// Scan pass 1: per-chunk aggregates over LCHUNK steps from c=0; A = prod(f).
// 4 channels/thread -> 131072 threads (2 waves/SIMD) for latency hiding.
// ---------------------------------------------------------------------------
__global__ __launch_bounds__(256) void scan_pass1(
    const _Float16* __restrict__ zbuf, const _Float16* __restrict__ fbuf,
    float* __restrict__ aggA, float* __restrict__ aggB) {
    const int idx = blockIdx.x * 256 + threadIdx.x;  // < B*NCHUNK*64 = 131072
    const int d4 = idx & 63;
    const int chunk = (idx >> 6) & (NCHUNK - 1);
    const int b = idx >> 14;

    const size_t row0 = (size_t)b * TDIM + (size_t)chunk * LCHUNK;
    const int2* zp = (const int2*)zbuf + row0 * 64 + d4;
    const int2* fp = (const int2*)fbuf + row0 * 64 + d4;

    float A[4], c[4];
#pragma unroll
    for (int e = 0; e < 4; ++e) { A[e] = 1.0f; c[e] = 0.0f; }

    for (int i = 0; i < LCHUNK; ++i) {
        int2 fv = *fp;
        int2 zv = *zp;
        const _Float16* fh = (const _Float16*)&fv;
        const _Float16* zh = (const _Float16*)&zv;
#pragma unroll
        for (int e = 0; e < 4; ++e) {
            const float f = (float)fh[e];
            const float z = (float)zh[e];
            A[e] *= f;
            c[e] = f * c[e] + (1.0f - f) * z;
        }
        fp += 64;
        zp += 64;
    }
    ((float4*)aggA)[idx] = make_float4(A[0], A[1], A[2], A[3]);
    ((float4*)aggB)[idx] = make_float4(c[0], c[1], c[2], c[3]);
}

// ---------------------------------------------------------------------------
// Carry scan across chunks: one thread per (b,d) = 2048 threads.
// Unroll-16 batched loads: 16 latency rounds instead of 32.
// ---------------------------------------------------------------------------
__global__ __launch_bounds__(256) void carry_scan(
    const float* __restrict__ aggA, const float* __restrict__ aggB,
    float* __restrict__ carry) {
    const int g = blockIdx.x * 256 + threadIdx.x;  // < B*D = 2048
    const int d = g & 255;
    const int b = g >> 8;
    const size_t base = (size_t)b * NCHUNK * 256 + d;

    float c = 0.0f;
    for (int ch0 = 0; ch0 < NCHUNK; ch0 += 16) {
        float A[16], Bv[16];
#pragma unroll
        for (int u = 0; u < 16; ++u) {
            const size_t p = base + (size_t)(ch0 + u) * 256;
            A[u] = aggA[p];
            Bv[u] = aggB[p];
        }
#pragma unroll
        for (int u = 0; u < 16; ++u) {
            const size_t p = base + (size_t)(ch0 + u) * 256;
            carry[p] = c;
            c = A[u] * c + Bv[u];
        }
    }
}

// ---------------------------------------------------------------------------
// Scan pass 2: replay chunk with true carry; h = o*c -> fp32 out.
// 4 channels/thread -> 131072 threads; one float4 store per step.
// ---------------------------------------------------------------------------
__global__ __launch_bounds__(256) void scan_pass2(
    const _Float16* __restrict__ zbuf, const _Float16* __restrict__ fbuf,
    const _Float16* __restrict__ obuf, const float* __restrict__ carry,
    float* __restrict__ out) {
    const int idx = blockIdx.x * 256 + threadIdx.x;  // < 131072
    const int d4 = idx & 63;
    const int chunk = (idx >> 6) & (NCHUNK - 1);
    const int b = idx >> 14;

    float c[4];
    const float4 c0 = ((const float4*)carry)[idx];
    c[0] = c0.x; c[1] = c0.y; c[2] = c0.z; c[3] = c0.w;

    const size_t row0 = (size_t)b * TDIM + (size_t)chunk * LCHUNK;
    const int2* zp = (const int2*)zbuf + row0 * 64 + d4;
    const int2* fp = (const int2*)fbuf + row0 * 64 + d4;
    const int2* op = (const int2*)obuf + row0 * 64 + d4;
    float4* hp = (float4*)out + row0 * 64 + d4;

    for (int i = 0; i < LCHUNK; ++i) {
        int2 fv = *fp;
        int2 zv = *zp;
        int2 ov = *op;
        const _Float16* fh = (const _Float16*)&fv;
        const _Float16* zh = (const _Float16*)&zv;
        const _Float16* oh = (const _Float16*)&ov;
        float h[4];
#pragma unroll
        for (int e = 0; e < 4; ++e) {
            const float f = (float)fh[e];
            const float z = (float)zh[e];
            c[e] = f * c[e] + (1.0f - f) * z;
            h[e] = (float)oh[e] * c[e];
        }
        *hp = make_float4(h[0], h[1], h[2], h[3]);
        fp += 64;
        zp += 64;
        op += 64;
        hp += 64;
    }
}

extern "C" void kernel_launch(void* const* d_in, const int* in_sizes, int n_in,
                              void* d_out, int out_size, void* d_ws,
                              size_t ws_size, hipStream_t stream) {
    const float* x = (const float*)d_in[0];
    const float* Wz = (const float*)d_in[1];
    const float* Wf = (const float*)d_in[2];
    const float* Wo = (const float*)d_in[3];
    const float* bz = (const float*)d_in[4];
    const float* bfv = (const float*)d_in[5];
    const float* bo = (const float*)d_in[6];
    float* out = (float*)d_out;

    // Workspace (bytes): xpad 16.78M | Wt 0.79M | z 16.78M | f 16.78M |
    // o 16.78M | aggA 2M | aggB 2M | carry 2M   -> ~74.7 MB
    char* p = (char*)d_ws;
    _Float16* xpad = (_Float16*)p;  p += (size_t)BDIM * (TDIM + 1) * DDIM * 2;
    _Float16* Wt = (_Float16*)p;    p += (size_t)3 * 256 * 512 * 2;
    _Float16* zbuf = (_Float16*)p;  p += (size_t)MDIM * DDIM * 2;
    _Float16* fbuf = (_Float16*)p;  p += (size_t)MDIM * DDIM * 2;
    _Float16* obuf = (_Float16*)p;  p += (size_t)MDIM * DDIM * 2;
    float* aggA = (float*)p;        p += (size_t)BDIM * NCHUNK * DDIM * 4;
    float* aggB = (float*)p;        p += (size_t)BDIM * NCHUNK * DDIM * 4;
    float* carry = (float*)p;

    prep<<<1536 + 1025 * BDIM, 256, 0, stream>>>(x, xpad, Wz, Wf, Wo, Wt);

    gates_mfma<<<MDIM / 128 * (DDIM / 128) * 3, 256, 0, stream>>>(
        xpad, Wt, bz, bfv, bo, zbuf, fbuf, obuf);

    scan_pass1<<<(BDIM * NCHUNK * 64) / 256, 256, 0, stream>>>(zbuf, fbuf,
                                                               aggA, aggB);
    carry_scan<<<(BDIM * DDIM) / 256, 256, 0, stream>>>(aggA, aggB, carry);
    scan_pass2<<<(BDIM * NCHUNK * 64) / 256, 256, 0, stream>>>(zbuf, fbuf,
                                                               obuf, carry, out);
}